// Round 15
// baseline (569.773 us; speedup 1.0000x reference)
//
#include <hip/hip_runtime.h>
#include <hip/hip_bf16.h>
#include <math.h>

#define HEADS 8
#define LL 4096
#define CDIM 256
#define BATCH 16
#define NROWS (BATCH*LL)

typedef __attribute__((ext_vector_type(8))) __bf16 bf16x8;
typedef __attribute__((ext_vector_type(4))) __bf16 bf16x4;
typedef __attribute__((ext_vector_type(4))) float f32x4;

__device__ inline float b2f(ushort u) {
    union { unsigned u; float f; } v; v.u = ((unsigned)u) << 16; return v.f;
}
__device__ inline ushort f2b(float f) {
    union { float f; unsigned u; } v; v.f = f;
    unsigned r = (v.u + 0x7FFF + ((v.u >> 16) & 1)) >> 16;
    return (ushort)r;
}
__device__ inline void gload16(const void* g, void* l) {
    __builtin_amdgcn_global_load_lds(
        (const __attribute__((address_space(1))) unsigned int*)g,
        (__attribute__((address_space(3))) unsigned int*)l, 16, 0, 0);
}
// tanh-form GELU (max ~1e-3 abs error vs erf form; below h1 bf16 noise)
__device__ inline float fast_gelu(float v) {
    float u = 0.7978845608028654f * v * (1.0f + 0.044715f * v * v);
    float e = exp2f(u * 2.885390081777927f);   // e^{2u}
    float t = 1.0f - 2.0f / (e + 1.0f);
    return 0.5f * v * (1.0f + t);
}

// ---------------------------------------------------------------------------
// Fused prep: pos/snc tables (blocks 0..1023), 6 weight transposes (1024..1791),
// ksglob zero (block 1792).
__global__ __launch_bounds__(256) void prep_kernel(
    float* __restrict__ pos, float* __restrict__ snc,
    const float* __restrict__ q_w, const float* __restrict__ k_w,
    const float* __restrict__ v_w, const float* __restrict__ o_w,
    const float* __restrict__ w1, const float* __restrict__ w2,
    ushort* __restrict__ wqT, ushort* __restrict__ wkT,
    ushort* __restrict__ wvT, ushort* __restrict__ woT,
    ushort* __restrict__ w1T, ushort* __restrict__ w2T,
    float* __restrict__ ksglob)
{
    __shared__ float t[32][33];
    int bid = blockIdx.x;
    int tid = threadIdx.x;
    if (bid == 1792) {
        for (int i = tid; i < BATCH * 2 * 256; i += 256) ksglob[i] = 0.0f;
        return;
    }
    if (bid < 1024) {
        int c = tid;
        int k = c & 63;
        float omega = expf(-(float)k * (9.210340371976184f / 64.0f));  // ln(10000)/64
        #pragma unroll
        for (int i = 0; i < 4; ++i) {
            int l = bid * 4 + i;
            int y = l >> 6, x = l & 63;
            float coord = (c < 128) ? (float)y : (float)x;
            float ang = coord * omega;
            float val = ((c & 127) < 64) ? sinf(ang) : cosf(ang);
            pos[l * CDIM + c] = val;
            if (c < 2) {
                float wi = 1.5707963267948966f * (float)(l + 1) / (float)LL;
                snc[l * 2 + c] = (c == 0) ? sinf(wi) : cosf(wi);
            }
        }
        return;
    }
    int id = bid - 1024;
    const float* W; ushort* Wt; int K, N, kb, nb;
    if (id < 64)       { W = q_w; Wt = wqT; K = 256;  N = 256;  kb = (id & 7) * 32;  nb = (id >> 3) * 32; }
    else if (id < 128) { id -= 64;  W = k_w; Wt = wkT; K = 256;  N = 256;  kb = (id & 7) * 32;  nb = (id >> 3) * 32; }
    else if (id < 192) { id -= 128; W = v_w; Wt = wvT; K = 256;  N = 256;  kb = (id & 7) * 32;  nb = (id >> 3) * 32; }
    else if (id < 256) { id -= 192; W = o_w; Wt = woT; K = 256;  N = 256;  kb = (id & 7) * 32;  nb = (id >> 3) * 32; }
    else if (id < 512) { id -= 256; W = w1;  Wt = w1T; K = 256;  N = 1024; kb = (id & 7) * 32;  nb = (id >> 3) * 32; }
    else               { id -= 512; W = w2;  Wt = w2T; K = 1024; N = 256;  kb = (id & 31) * 32; nb = (id >> 5) * 32; }
    int x = tid & 31, y = tid >> 5;
    #pragma unroll
    for (int i = 0; i < 4; ++i)
        t[y + i * 8][x] = W[(size_t)(kb + y + i * 8) * N + nb + x];
    __syncthreads();
    #pragma unroll
    for (int i = 0; i < 4; ++i) {
        int n = y + i * 8;
        Wt[(size_t)(nb + n) * K + kb + x] = f2b(t[x][n]);
    }
}

// ---------------------------------------------------------------------------
// Merged: z<16 -> a3 avgpool2 -> residual bf16 + x3 bf16 (+pos table)
//         z>=16 -> a4 transpose -> x4 bf16 (+pos table)
__global__ __launch_bounds__(256) void pool_x4_kernel(
    const float* __restrict__ a3, const float* __restrict__ a4,
    ushort* __restrict__ residual, ushort* __restrict__ x3b,
    ushort* __restrict__ x4b, const float* __restrict__ pos)
{
    __shared__ float raw[64][128];
    __shared__ float pooled[64][65];
    int tid = threadIdx.x;
    int ct = blockIdx.y;
    if (blockIdx.z < 16) {
        int i = blockIdx.x, b = blockIdx.z;
        #pragma unroll
        for (int it = 0; it < 8; ++it) {
            int lin = (it * 256 + tid) * 4;
            int x = lin & 127;
            int cc = lin >> 7;
            size_t base = ((size_t)(b * 256 + ct * 64 + cc) * 128 + 2 * i) * 128 + x;
            float4 v0 = *(const float4*)&a3[base];
            float4 v1 = *(const float4*)&a3[base + 128];
            float4 s = make_float4(v0.x + v1.x, v0.y + v1.y, v0.z + v1.z, v0.w + v1.w);
            *(float4*)&raw[cc][x] = s;
        }
        __syncthreads();
        #pragma unroll
        for (int it = 0; it < 16; ++it) {
            int idx = it * 256 + tid;
            int j = idx & 63, cc = idx >> 6;
            pooled[cc][j] = 0.25f * (raw[cc][2 * j] + raw[cc][2 * j + 1]);
        }
        __syncthreads();
        #pragma unroll
        for (int it = 0; it < 16; ++it) {
            int cc = tid & 63;
            int jj = (tid >> 6) + it * 4;
            float val = pooled[cc][jj];
            int l = i * 64 + jj;
            int c = ct * 64 + cc;
            size_t o = (size_t)(b * LL + l) * CDIM + c;
            residual[o] = f2b(val);
            x3b[o] = f2b(val + pos[l * CDIM + c]);
        }
    } else {
        int y = blockIdx.x, b = blockIdx.z - 16;
        #pragma unroll
        for (int it = 0; it < 16; ++it) {
            int idx = it * 256 + tid;
            int x = idx & 63, cc = idx >> 6;
            pooled[cc][x] = a4[((size_t)(b * 256 + ct * 64 + cc) * 64 + y) * 64 + x];
        }
        __syncthreads();
        #pragma unroll
        for (int it = 0; it < 16; ++it) {
            int cc = tid & 63;
            int xx = (tid >> 6) + it * 4;
            int l = y * 64 + xx, c = ct * 64 + cc;
            x4b[(size_t)(b * LL + l) * CDIM + c] = f2b(pooled[cc][xx] + pos[l * CDIM + c]);
        }
    }
}

// ---------------------------------------------------------------------------
// MFMA GEMM (K=256, cols=256): out = epilogue(A @ Wt^T + bias) [+ res].
// 128 rows x 256 cols per block, 512 thr = 8 waves (2 row x 4 col), 64x64/wave.
// 2-phase double-buffered, 1 barrier/step.
template<bool DO_LN, bool DO_RELU, bool DO_RES>
__global__ __launch_bounds__(512, 4) void gemm_mfma(
    const ushort* __restrict__ A, const ushort* __restrict__ Wt,
    const float* __restrict__ bias, const float* __restrict__ gam_,
    const float* __restrict__ bet_, const ushort* __restrict__ res,
    ushort* __restrict__ outb)
{
    __shared__ ushort As[2][128 * 32];   // 8 KB each
    __shared__ ushort Bs[2][256 * 32];   // 16 KB each
    __shared__ float redS[128][4];
    __shared__ float redQ[128][4];
    __shared__ float2 mustd[128];

    const int tid = threadIdx.x;
    const int lane = tid & 63;
    const int wv = tid >> 6;     // 0..7
    const int wr = wv >> 2;      // 0..1
    const int wc = wv & 3;       // 0..3
    const int wvu = __builtin_amdgcn_readfirstlane(wv);
    const int row0 = blockIdx.x * 128;

    const int sr = tid >> 2;                      // 0..127
    const int sg = (tid & 3) ^ ((sr >> 1) & 3);   // swizzled source k-group
    const ushort* aSrc = A + (size_t)(row0 + sr) * 256 + sg * 8;
    const ushort* bSrc0 = Wt + (size_t)sr * 256 + sg * 8;
    const ushort* bSrc1 = Wt + (size_t)(128 + sr) * 256 + sg * 8;

    const int frSlot = (lane >> 4) ^ (((lane & 15) >> 1) & 3);

    f32x4 acc[4][4] = {};
    gload16(aSrc, (char*)&As[0][0] + wvu * 1024);
    gload16(bSrc0, (char*)&Bs[0][0] + wvu * 1024);
    gload16(bSrc1, (char*)&Bs[0][0] + 8192 + wvu * 1024);
    __syncthreads();

    int cur = 0;
    for (int t = 0; t < 8; ++t) {
        if (t < 7) {
            gload16(aSrc + (t + 1) * 32, (char*)&As[cur ^ 1][0] + wvu * 1024);
            gload16(bSrc0 + (t + 1) * 32, (char*)&Bs[cur ^ 1][0] + wvu * 1024);
            gload16(bSrc1 + (t + 1) * 32, (char*)&Bs[cur ^ 1][0] + 8192 + wvu * 1024);
        }
        bf16x8 af[4], bfr[4];
        #pragma unroll
        for (int f = 0; f < 4; ++f) {
            int r = wr * 64 + f * 16 + (lane & 15);
            af[f] = *(const bf16x8*)&As[cur][r * 32 + frSlot * 8];
            int c = wc * 64 + f * 16 + (lane & 15);
            bfr[f] = *(const bf16x8*)&Bs[cur][c * 32 + frSlot * 8];
        }
        __builtin_amdgcn_s_setprio(1);
        #pragma unroll
        for (int fi = 0; fi < 4; ++fi)
            #pragma unroll
            for (int fj = 0; fj < 4; ++fj)
                acc[fi][fj] = __builtin_amdgcn_mfma_f32_16x16x32_bf16(
                    af[fi], bfr[fj], acc[fi][fj], 0, 0, 0);
        __builtin_amdgcn_s_setprio(0);
        __syncthreads();
        cur ^= 1;
    }

    const int cl = lane & 15;
    const int rg = lane >> 4;
    float bia[4], gmv[4], btv[4];
    #pragma unroll
    for (int fj = 0; fj < 4; ++fj) {
        int col = wc * 64 + fj * 16 + cl;
        bia[fj] = bias[col];
        if constexpr (DO_LN) { gmv[fj] = gam_[col]; btv[fj] = bet_[col]; }
    }
    #pragma unroll
    for (int fi = 0; fi < 4; ++fi)
        #pragma unroll
        for (int fj = 0; fj < 4; ++fj)
            #pragma unroll
            for (int j = 0; j < 4; ++j)
                acc[fi][fj][j] += bia[fj];

    if constexpr (DO_LN) {
        #pragma unroll
        for (int fi = 0; fi < 4; ++fi)
            #pragma unroll
            for (int j = 0; j < 4; ++j) {
                float s = acc[fi][0][j] + acc[fi][1][j] + acc[fi][2][j] + acc[fi][3][j];
                float q = acc[fi][0][j] * acc[fi][0][j] + acc[fi][1][j] * acc[fi][1][j]
                        + acc[fi][2][j] * acc[fi][2][j] + acc[fi][3][j] * acc[fi][3][j];
                #pragma unroll
                for (int m = 1; m <= 8; m <<= 1) {
                    s += __shfl_xor(s, m, 64);
                    q += __shfl_xor(q, m, 64);
                }
                if (cl == 0) {
                    int tr = wr * 64 + fi * 16 + rg * 4 + j;
                    redS[tr][wc] = s; redQ[tr][wc] = q;
                }
            }
        __syncthreads();
        if (tid < 128) {
            float s = redS[tid][0] + redS[tid][1] + redS[tid][2] + redS[tid][3];
            float q = redQ[tid][0] + redQ[tid][1] + redQ[tid][2] + redQ[tid][3];
            float mu = s * (1.0f / 256.0f);
            float var = q * (1.0f / 256.0f) - mu * mu;
            mustd[tid] = make_float2(mu, rsqrtf(var + 1e-5f));
        }
        __syncthreads();
        #pragma unroll
        for (int fi = 0; fi < 4; ++fi)
            #pragma unroll
            for (int j = 0; j < 4; ++j) {
                float2 ms = mustd[wr * 64 + fi * 16 + rg * 4 + j];
                #pragma unroll
                for (int fj = 0; fj < 4; ++fj)
                    acc[fi][fj][j] = (acc[fi][fj][j] - ms.x) * ms.y * gmv[fj] + btv[fj];
            }
    }
    if constexpr (DO_RELU) {
        #pragma unroll
        for (int fi = 0; fi < 4; ++fi)
            #pragma unroll
            for (int fj = 0; fj < 4; ++fj)
                #pragma unroll
                for (int j = 0; j < 4; ++j)
                    acc[fi][fj][j] = fmaxf(acc[fi][fj][j], 0.0f);
    }
    #pragma unroll
    for (int fi = 0; fi < 4; ++fi)
        #pragma unroll
        for (int j = 0; j < 4; ++j) {
            size_t row = row0 + wr * 64 + fi * 16 + rg * 4 + j;
            size_t rbase = row * 256 + wc * 64 + cl;
            #pragma unroll
            for (int fj = 0; fj < 4; ++fj) {
                float v = acc[fi][fj][j];
                if constexpr (DO_RES) v += b2f(res[rbase + fj * 16]);
                outb[rbase + fj * 16] = f2b(v);
            }
        }
}

// ---------------------------------------------------------------------------
// Fused K+V GEMM (128 rows, 512 thr, dbuf): K = relu(LN(x4@k_w+k_b)), V = x4@v_w+v_b.
// Reduction scratch aliased into As (dead after K-loop) -> 80 KB LDS -> 2 blocks/CU.
__global__ __launch_bounds__(512, 2) void gemm_kv(
    const ushort* __restrict__ A, const ushort* __restrict__ wkT,
    const ushort* __restrict__ wvT, const float* __restrict__ k_b,
    const float* __restrict__ k_g, const float* __restrict__ k_beta,
    const float* __restrict__ v_b, const float* __restrict__ snc,
    float* __restrict__ ksglob, ushort* __restrict__ Kb, ushort* __restrict__ Vb)
{
    __shared__ ushort As[2][128 * 32];    // 8 KB each; epilogue reuses as scratch
    __shared__ ushort BsK[2][256 * 32];   // 16 KB each
    __shared__ ushort BsV[2][256 * 32];
    float*  redS  = (float*)&As[0][0];        // [128][4]
    float*  redQ  = redS + 512;
    float2* mustd = (float2*)(redQ + 512);

    const int tid = threadIdx.x;
    const int lane = tid & 63;
    const int wv = tid >> 6;
    const int wr = wv >> 2;
    const int wc = wv & 3;
    const int wvu = __builtin_amdgcn_readfirstlane(wv);
    const int row0 = blockIdx.x * 128;

    const int sr = tid >> 2;
    const int sg = (tid & 3) ^ ((sr >> 1) & 3);
    const ushort* aSrc = A + (size_t)(row0 + sr) * 256 + sg * 8;
    const ushort* bkSrc0 = wkT + (size_t)sr * 256 + sg * 8;
    const ushort* bkSrc1 = wkT + (size_t)(128 + sr) * 256 + sg * 8;
    const ushort* bvSrc0 = wvT + (size_t)sr * 256 + sg * 8;
    const ushort* bvSrc1 = wvT + (size_t)(128 + sr) * 256 + sg * 8;

    const int frSlot = (lane >> 4) ^ (((lane & 15) >> 1) & 3);

    f32x4 accK[4][4] = {};
    f32x4 accV[4][4] = {};
    gload16(aSrc, (char*)&As[0][0] + wvu * 1024);
    gload16(bkSrc0, (char*)&BsK[0][0] + wvu * 1024);
    gload16(bkSrc1, (char*)&BsK[0][0] + 8192 + wvu * 1024);
    gload16(bvSrc0, (char*)&BsV[0][0] + wvu * 1024);
    gload16(bvSrc1, (char*)&BsV[0][0] + 8192 + wvu * 1024);
    __syncthreads();

    int cur = 0;
    for (int t = 0; t < 8; ++t) {
        if (t < 7) {
            gload16(aSrc + (t + 1) * 32, (char*)&As[cur ^ 1][0] + wvu * 1024);
            gload16(bkSrc0 + (t + 1) * 32, (char*)&BsK[cur ^ 1][0] + wvu * 1024);
            gload16(bkSrc1 + (t + 1) * 32, (char*)&BsK[cur ^ 1][0] + 8192 + wvu * 1024);
            gload16(bvSrc0 + (t + 1) * 32, (char*)&BsV[cur ^ 1][0] + wvu * 1024);
            gload16(bvSrc1 + (t + 1) * 32, (char*)&BsV[cur ^ 1][0] + 8192 + wvu * 1024);
        }
        bf16x8 af[4], bk[4], bv[4];
        #pragma unroll
        for (int f = 0; f < 4; ++f) {
            int r = wr * 64 + f * 16 + (lane & 15);
            af[f] = *(const bf16x8*)&As[cur][r * 32 + frSlot * 8];
            int c = wc * 64 + f * 16 + (lane & 15);
            bk[f] = *(const bf16x8*)&BsK[cur][c * 32 + frSlot * 8];
            bv[f] = *(const bf16x8*)&BsV[cur][c * 32 + frSlot * 8];
        }
        __builtin_amdgcn_s_setprio(1);
        #pragma unroll
        for (int fi = 0; fi < 4; ++fi)
            #pragma unroll
            for (int fj = 0; fj < 4; ++fj) {
                accK[fi][fj] = __builtin_amdgcn_mfma_f32_16x16x32_bf16(
                    af[fi], bk[fj], accK[fi][fj], 0, 0, 0);
                accV[fi][fj] = __builtin_amdgcn_mfma_f32_16x16x32_bf16(
                    af[fi], bv[fj], accV[fi][fj], 0, 0, 0);
            }
        __builtin_amdgcn_s_setprio(0);
        __syncthreads();
        cur ^= 1;
    }

    const int cl = lane & 15;
    const int rg = lane >> 4;
    // ---- V epilogue ----
    #pragma unroll
    for (int fj = 0; fj < 4; ++fj) {
        float bv_ = v_b[wc * 64 + fj * 16 + cl];
        #pragma unroll
        for (int fi = 0; fi < 4; ++fi)
            #pragma unroll
            for (int j = 0; j < 4; ++j)
                accV[fi][fj][j] += bv_;
    }
    #pragma unroll
    for (int fi = 0; fi < 4; ++fi)
        #pragma unroll
        for (int j = 0; j < 4; ++j) {
            size_t rbase = (size_t)(row0 + wr * 64 + fi * 16 + rg * 4 + j) * 256 + wc * 64 + cl;
            #pragma unroll
            for (int fj = 0; fj < 4; ++fj)
                Vb[rbase + fj * 16] = f2b(accV[fi][fj][j]);
        }
    // ---- K epilogue: bias + LN + relu + ksum + store ----
    float bia[4], gmv[4], btv[4];
    #pragma unroll
    for (int fj = 0; fj < 4; ++fj) {
        int col = wc * 64 + fj * 16 + cl;
        bia[fj] = k_b[col]; gmv[fj] = k_g[col]; btv[fj] = k_beta[col];
    }
    #pragma unroll
    for (int fi = 0; fi < 4; ++fi)
        #pragma unroll
        for (int fj = 0; fj < 4; ++fj)
            #pragma unroll
            for (int j = 0; j < 4; ++j)
                accK[fi][fj][j] += bia[fj];
    #pragma unroll
    for (int fi = 0; fi < 4; ++fi)
        #pragma unroll
        for (int j = 0; j < 4; ++j) {
            float s = accK[fi][0][j] + accK[fi][1][j] + accK[fi][2][j] + accK[fi][3][j];
            float q = accK[fi][0][j] * accK[fi][0][j] + accK[fi][1][j] * accK[fi][1][j]
                    + accK[fi][2][j] * accK[fi][2][j] + accK[fi][3][j] * accK[fi][3][j];
            #pragma unroll
            for (int m = 1; m <= 8; m <<= 1) {
                s += __shfl_xor(s, m, 64);
                q += __shfl_xor(q, m, 64);
            }
            if (cl == 0) {
                int tr = wr * 64 + fi * 16 + rg * 4 + j;
                redS[tr * 4 + wc] = s; redQ[tr * 4 + wc] = q;
            }
        }
    __syncthreads();
    if (tid < 128) {
        float s = redS[tid * 4] + redS[tid * 4 + 1] + redS[tid * 4 + 2] + redS[tid * 4 + 3];
        float q = redQ[tid * 4] + redQ[tid * 4 + 1] + redQ[tid * 4 + 2] + redQ[tid * 4 + 3];
        float mu = s * (1.0f / 256.0f);
        float var = q * (1.0f / 256.0f) - mu * mu;
        mustd[tid] = make_float2(mu, rsqrtf(var + 1e-5f));
    }
    __syncthreads();
    float kss[4] = {}, ksc[4] = {};
    #pragma unroll
    for (int fi = 0; fi < 4; ++fi)
        #pragma unroll
        for (int j = 0; j < 4; ++j) {
            int rloc = wr * 64 + fi * 16 + rg * 4 + j;
            float2 ms = mustd[rloc];
            int l = (row0 + rloc) & (LL - 1);
            float sn = snc[l * 2], cs = snc[l * 2 + 1];
            size_t rbase = (size_t)(row0 + rloc) * 256 + wc * 64 + cl;
            #pragma unroll
            for (int fj = 0; fj < 4; ++fj) {
                float v = (accK[fi][fj][j] - ms.x) * ms.y * gmv[fj] + btv[fj];
                v = fmaxf(v, 0.0f);
                Kb[rbase + fj * 16] = f2b(v);
                kss[fj] += sn * v;
                ksc[fj] += cs * v;
            }
        }
    int b = row0 >> 12;
    #pragma unroll
    for (int fj = 0; fj < 4; ++fj) {
        float s = kss[fj], c = ksc[fj];
        s += __shfl_xor(s, 16, 64); s += __shfl_xor(s, 32, 64);
        c += __shfl_xor(c, 16, 64); c += __shfl_xor(c, 32, 64);
        if (rg == 0) {
            int col = wc * 64 + fj * 16 + cl;
            atomicAdd(&ksglob[((size_t)b * 2 + 0) * 256 + col], s);
            atomicAdd(&ksglob[((size_t)b * 2 + 1) * 256 + col], c);
        }
    }
}

// ---------------------------------------------------------------------------
// Fused MLP: out = LN2(gelu(res2@W1+b1)@W2+b2) + res2.
// 64 rows/block, 4 chunks of 256 h1-cols; h1 chunk in LDS as [t][64][36] (padded).
__global__ __launch_bounds__(256, 2) void mlp_fused(
    const ushort* __restrict__ res2, const ushort* __restrict__ w1T,
    const ushort* __restrict__ w2T, const float* __restrict__ b1,
    const float* __restrict__ b2, const float* __restrict__ gam_,
    const float* __restrict__ bet_, ushort* __restrict__ outb)
{
    __shared__ ushort As[2][64 * 32];
    __shared__ ushort Bs[2][256 * 32];
    __shared__ ushort h1c[8 * 64 * 36];   // 36 KB, 72B row stride (odd dword count)
    __shared__ float redS[64][4];
    __shared__ float redQ[64][4];
    __shared__ float2 mustd[64];

    const int tid = threadIdx.x;
    const int lane = tid & 63;
    const int wv = tid >> 6;
    const int wvu = __builtin_amdgcn_readfirstlane(wv);
    const int row0 = blockIdx.x * 64;
    const int sr = tid >> 2;
    const int sg = (tid & 3) ^ ((sr >> 1) & 3);
    const ushort* aSrc = res2 + (size_t)(row0 + sr) * 256 + sg * 8;
    const int frSlot = (lane >> 4) ^ (((lane & 15) >> 1) & 3);
    const int cl = lane & 15;
    const int rg = lane >> 4;

    f32x4 acc2[4][4] = {};
    gload16(aSrc, (char*)&As[0][0] + wvu * 1024);
    #pragma unroll
    for (int j = 0; j < 4; ++j)
        gload16(w1T + (size_t)(j * 64 + sr) * 256 + sg * 8,
                (char*)&Bs[0][0] + j * 4096 + wvu * 1024);
    __syncthreads();
    int cur = 0;

    for (int c = 0; c < 4; ++c) {
        const ushort* b1Src = w1T + (size_t)(c * 256 + sr) * 256 + sg * 8;
        const ushort* b2Src = w2T + (size_t)sr * 1024 + c * 256 + sg * 8;
        f32x4 acc1[4][4] = {};
        // ---- GEMM1 over K=256 (8 steps) ----
        for (int t = 0; t < 8; ++t) {
            if (t < 7) {
                gload16(aSrc + (t + 1) * 32, (char*)&As[cur ^ 1][0] + wvu * 1024);
                #pragma unroll
                for (int j = 0; j < 4; ++j)
                    gload16(b1Src + j * 64 * 256 + (t + 1) * 32,
                            (char*)&Bs[cur ^ 1][0] + j * 4096 + wvu * 1024);
            } else {
                gload16(aSrc, (char*)&As[cur ^ 1][0] + wvu * 1024);
                #pragma unroll
                for (int j = 0; j < 4; ++j)
                    gload16(b2Src + (size_t)j * 64 * 1024,
                            (char*)&Bs[cur ^ 1][0] + j * 4096 + wvu * 1024);
            }
            bf16x8 af[4], bfr[4];
            #pragma unroll
            for (int f = 0; f < 4; ++f) {
                int r = f * 16 + (lane & 15);
                af[f] = *(const bf16x8*)&As[cur][r * 32 + frSlot * 8];
                int cc2 = wv * 64 + f * 16 + (lane & 15);
                bfr[f] = *(const bf16x8*)&Bs[cur][cc2 * 32 + frSlot * 8];
            }
            __builtin_amdgcn_s_setprio(1);
            #pragma unroll
            for (int fi = 0; fi < 4; ++fi)
                #pragma unroll
                for (int fj = 0; fj < 4; ++fj)
                    acc1[fi][fj] = __builtin_amdgcn_mfma_f32_16x16x32_bf16(
                        af[fi], bfr[fj], acc1[fi][fj], 0, 0, 0);
            __builtin_amdgcn_s_setprio(0);
            __syncthreads();
            cur ^= 1;
        }
        // ---- epilogue1: bias + fast gelu -> h1c ----
        float bia1[4];
        #pragma unroll
        for (int fj = 0; fj < 4; ++fj)
            bia1[fj] = b1[c * 256 + wv * 64 + fj * 16 + cl];
        #pragma unroll
        for (int fi = 0; fi < 4; ++fi)
            #pragma unroll
            for (int fj = 0; fj < 4; ++fj) {
                int tch = wv * 2 + (fj >> 1);
                int kk_local = (fj & 1) * 16 + cl;
                #pragma unroll
                for (int j = 0; j < 4; ++j) {
                    float v = acc1[fi][fj][j] + bia1[fj];
                    float g = fast_gelu(v);
                    int row = fi * 16 + rg * 4 + j;
                    h1c[tch * 2304 + row * 36 + kk_local] = f2b(g);
                }
            }
        __syncthreads();
        // ---- GEMM2 over this chunk's K=256 (8 steps) ----
        for (int t = 0; t < 8; ++t) {
            if (t < 7) {
                #pragma unroll
                for (int j = 0; j < 4; ++j)
                    gload16(b2Src + (size_t)j * 64 * 1024 + (t + 1) * 32,
                            (char*)&Bs[cur ^ 1][0] + j * 4096 + wvu * 1024);
            } else {
                int cn = (c < 3) ? c + 1 : 3;
                #pragma unroll
                for (int j = 0; j < 4; ++j)
                    gload16(w1T + (size_t)(cn * 256 + j * 64 + sr) * 256 + sg * 8,
                            (char*)&Bs[cur ^ 1][0] + j * 4096 + wvu * 1024);
            }
            bf16x8 af[4], bfr[4];
            #pragma unroll
            for (int f = 0; f < 4; ++f) {
                int r = f * 16 + (lane & 15);
                int ho = t * 2304 + r * 36 + (lane >> 4) * 8;
                bf16x4 lo = *(const bf16x4*)&h1c[ho];
                bf16x4 hi = *(const bf16x4*)&h1c[ho + 4];
                bf16x8 a_;
                a_[0] = lo[0]; a_[1] = lo[1]; a_[2] = lo[2]; a_[3] = lo[3];
                a_[4] = hi[0]; a_[5] = hi[1]; a_[6] = hi[2]; a_[7] = hi[3];
                af[f] = a_;
                int cc2 = wv * 64 + f * 16 + (lane & 15);
                bfr[f] = *(const bf16x8*)&Bs[cur][cc2 * 32 + frSlot * 8];
            }
            __builtin_amdgcn_s_setprio(1);
            #pragma unroll
            for (int fi = 0; fi < 4; ++fi)
                #pragma unroll
                for (int fj = 0; fj < 4; ++fj)
                    acc2[fi][fj] = __builtin_amdgcn_mfma_f32_16x16x32_bf16(
                        af[fi], bfr[fj], acc2[fi][fj], 0, 0, 0);
            __builtin_amdgcn_s_setprio(0);
            __syncthreads();
            cur ^= 1;
        }
    }
    // ---- epilogue2: + b2, LN(n2), + res2 residual, write bf16 ----
    float bia[4], gmv[4], btv[4];
    #pragma unroll
    for (int fj = 0; fj < 4; ++fj) {
        int col = wv * 64 + fj * 16 + cl;
        bia[fj] = b2[col];
        gmv[fj] = gam_[col];
        btv[fj] = bet_[col];
    }
    #pragma unroll
    for (int fi = 0; fi < 4; ++fi)
        #pragma unroll
        for (int fj = 0; fj < 4; ++fj)
            #pragma unroll
            for (int j = 0; j < 4; ++j)
                acc2[fi][fj][j] += bia[fj];
    #pragma unroll
    for (int fi = 0; fi < 4; ++fi)
        #pragma unroll
        for (int j = 0; j < 4; ++j) {
            float s = acc2[fi][0][j] + acc2[fi][1][j] + acc2[fi][2][j] + acc2[fi][3][j];
            float q = acc2[fi][0][j] * acc2[fi][0][j] + acc2[fi][1][j] * acc2[fi][1][j]
                    + acc2[fi][2][j] * acc2[fi][2][j] + acc2[fi][3][j] * acc2[fi][3][j];
            #pragma unroll
            for (int m = 1; m <= 8; m <<= 1) {
                s += __shfl_xor(s, m, 64);
                q += __shfl_xor(q, m, 64);
            }
            if (cl == 0) { redS[fi * 16 + rg * 4 + j][wv] = s; redQ[fi * 16 + rg * 4 + j][wv] = q; }
        }
    __syncthreads();
    if (tid < 64) {
        float s = redS[tid][0] + redS[tid][1] + redS[tid][2] + redS[tid][3];
        float q = redQ[tid][0] + redQ[tid][1] + redQ[tid][2] + redQ[tid][3];
        float mu = s * (1.0f / 256.0f);
        float var = q * (1.0f / 256.0f) - mu * mu;
        mustd[tid] = make_float2(mu, rsqrtf(var + 1e-5f));
    }
    __syncthreads();
    #pragma unroll
    for (int fi = 0; fi < 4; ++fi)
        #pragma unroll
        for (int j = 0; j < 4; ++j) {
            float2 ms = mustd[fi * 16 + rg * 4 + j];
            size_t row = row0 + fi * 16 + rg * 4 + j;
            size_t rbase = row * 256 + wv * 64 + cl;
            #pragma unroll
            for (int fj = 0; fj < 4; ++fj) {
                float v = (acc2[fi][fj][j] - ms.x) * ms.y * gmv[fj] + btv[fj];
                v += b2f(res2[rbase + fj * 16]);
                outb[rbase + fj * 16] = f2b(v);
            }
        }
}

// ---------------------------------------------------------------------------
// cosFormer stage 1: partial KVs/KVc (32x32) per (b,h,chunk). Stride 2048.
__global__ __launch_bounds__(256) void kv_kernel(
    const ushort* __restrict__ Kmat, const ushort* __restrict__ Vmat,
    const float* __restrict__ snc, float* __restrict__ kvpart)
{
    __shared__ float Kt[64][36];
    __shared__ float Vt[64][36];
    __shared__ float sns[64], css[64];
    int chunk = blockIdx.x;
    int bh = blockIdx.y;
    int b = bh >> 3, h = bh & 7;
    int tid = threadIdx.x;
    int m = tid & 31;
    int d0 = (tid >> 5) * 4;
    float accs[4] = {}, accc[4] = {};
    int l0chunk = chunk * 512;
    int lrow = tid >> 2;
    int lcol = (tid & 3) * 8;
    for (int sub = 0; sub < 8; ++sub) {
        int l0 = l0chunk + sub * 64;
        {
            size_t gbase = (size_t)(b * LL + l0 + lrow) * CDIM + h * 32 + lcol;
            uint4 kr = *(const uint4*)&Kmat[gbase];
            uint4 vr = *(const uint4*)&Vmat[gbase];
            float* kd = &Kt[lrow][lcol];
            float* vd = &Vt[lrow][lcol];
            kd[0] = b2f((ushort)(kr.x & 0xffff)); kd[1] = b2f((ushort)(kr.x >> 16));
            kd[2] = b2f((ushort)(kr.y & 0xffff)); kd[3] = b2f((ushort)(kr.y >> 16));
            kd[4] = b2f((ushort)(kr.z & 0xffff)); kd[5] = b2f((ushort)(kr.z >> 16));
            kd[6] = b2f((ushort)(kr.w & 0xffff)); kd[7] = b2f((ushort)(kr.w >> 16));
            vd[0] = b2f((ushort)(vr.x & 0xffff)); vd[1] = b2f((ushort)(vr.x >> 16));
            vd[2] = b2f((ushort)(vr.y & 0xffff)); vd[3] = b2f((ushort)(vr.y >> 16));
            vd[4] = b2f((ushort)(vr.z & 0xffff)); vd[5] = b2f((ushort)(vr.z >> 16));
            vd[6] = b2f((ushort)(vr.w & 0xffff)); vd[7] = b2f((ushort)(vr.w >> 16));
        }
        if (tid < 64) { sns[tid] = snc[(l0 + tid) * 2]; css[tid] = snc[(l0 + tid) * 2 + 1]; }
        __syncthreads();
        #pragma unroll 4
        for (int lt = 0; lt < 64; ++lt) {
            float v = Vt[lt][m];
            float vs = v * sns[lt];
            float vc = v * css[lt];
            float4 kd4 = *(const float4*)&Kt[lt][d0];
            accs[0] += kd4.x * vs; accc[0] += kd4.x * vc;
            accs[1] += kd4.y * vs; accc[1] += kd4.y * vc;
            accs[2] += kd4.z * vs; accc[2] += kd4.z * vc;
            accs[3] += kd4.w * vs; accc[3] += kd4.w * vc;
        }
        __syncthreads();
    }
    size_t base = (size_t)(bh * 8 + chunk) * 2048;
    #pragma unroll
    for (int i2 = 0; i2 < 4; ++i2) {
        kvpart[base + (d0 + i2) * 32 + m] = accs[i2];
        kvpart[base + 1024 + (d0 + i2) * 32 + m] = accc[i2];
    }
}

// ---------------------------------------------------------------------------
// attn via MFMA (kvred folded in): per (ltile, h, b): 256 rows.
// Each block reduces the 8 kvpart chunks + ksglob into its LDS B-image
// (hi/lo bf16 split, identical math to the old kvred kernel).
__global__ __launch_bounds__(256, 2) void attn_mfma(
    const ushort* __restrict__ Qmat, const float* __restrict__ kvpart,
    const float* __restrict__ ksglob, const float* __restrict__ snc,
    ushort* __restrict__ attnOut)
{
    __shared__ ushort Bs[5120];
    int ltile = blockIdx.x, h = blockIdx.y, b = blockIdx.z;
    int bh = b * 8 + h;
    int tid = threadIdx.x;
    int lane = tid & 63;
    int wv = tid >> 6;

    for (int e = tid; e < 2560; e += 256) {
        int n = e >> 5;
        int k = e & 31;
        int t = n >> 4, col = n & 15;
        float v = 0.0f;
        if (t < 4) {
            int off = (t >= 2 ? 1024 : 0) + k * 32 + (t & 1) * 16 + col;
            #pragma unroll
            for (int ch = 0; ch < 8; ++ch)
                v += kvpart[(size_t)(bh * 8 + ch) * 2048 + off];
        } else if (col < 2) {
            v = ksglob[((size_t)b * 2 + col) * 256 + h * 32 + k];
        }
        ushort hi = f2b(v);
        ushort lo = f2b(v - b2f(hi));
        Bs[n * 32 + k] = hi;
        Bs[(80 + n) * 32 + k] = lo;
    }
    __syncthreads();

    bf16x8 bfr[10];
    #pragma unroll
    for (int tt = 0; tt < 10; ++tt) {
        int row = (tt < 5 ? tt * 16 : 80 + (tt - 5) * 16) + (lane & 15);
        bfr[tt] = *(const bf16x8*)&Bs[row * 32 + (lane >> 4) * 8];
    }
    int lbase = ltile * 256 + wv * 64;
    bf16x8 af[4];
    #pragma unroll
    for (int fi = 0; fi < 4; ++fi) {
        int l = lbase + fi * 16 + (lane & 15);
        af[fi] = *(const bf16x8*)&Qmat[(size_t)(b * LL + l) * CDIM + h * 32 + (lane >> 4) * 8];
    }
    f32x4 acc[4][5] = {};
    __builtin_amdgcn_s_setprio(1);
    #pragma unroll
    for (int fi = 0; fi < 4; ++fi)
        #pragma unroll
        for (int t = 0; t < 5; ++t) {
            acc[fi][t] = __builtin_amdgcn_mfma_f32_16x16x32_bf16(af[fi], bfr[t], acc[fi][t], 0, 0, 0);
            acc[fi][t] = __builtin_amdgcn_mfma_f32_16x16x32_bf16(af[fi], bfr[t + 5], acc[fi][t], 0, 0, 0);
        }
    __builtin_amdgcn_s_setprio(0);

    int zlane = lane & 48;
    int cl = lane & 15;
    #pragma unroll
    for (int fi = 0; fi < 4; ++fi) {
        #pragma unroll
        for (int j = 0; j < 4; ++j) {
            float zraw = acc[fi][4][j];
            float zs = __shfl(zraw, zlane, 64);
            float zc = __shfl(zraw, zlane | 1, 64);
            int l = lbase + fi * 16 + ((lane >> 4) & 3) * 4 + j;
            float sn = snc[l * 2], cs = snc[l * 2 + 1];
            float den = sn * zs + cs * zc;
            float Z = 1.0f / fmaxf(den, 1e-6f);
            float v0 = (sn * acc[fi][0][j] + cs * acc[fi][2][j]) * Z;
            float v1 = (sn * acc[fi][1][j] + cs * acc[fi][3][j]) * Z;
            size_t ob = (size_t)(b * LL + l) * CDIM + h * 32 + cl;
            attnOut[ob] = f2b(v0);
            attnOut[ob + 16] = f2b(v1);
        }
    }
}

// ---------------------------------------------------------------------------
// ffeat bf16 (b,L,256) -> (b,c,64,64) -> bilinear x2 * a3 -> out f32
// Vectorized ffeat loads: uint4 = 8 bf16 per load (6 loads/thread).
__global__ __launch_bounds__(256) void resize_mul_kernel(
    const ushort* __restrict__ ffeat, const float* __restrict__ a3, float* __restrict__ out)
{
    __shared__ float ft[3][64][65];
    int k = blockIdx.x, ct = blockIdx.y, b = blockIdx.z;
    int tid = threadIdx.x;
    #pragma unroll
    for (int it = 0; it < 6; ++it) {
        int e = it * 256 + tid;        // 0..1535
        int cg = e & 7;                // col-group of 8 bf16
        int xs = (e >> 3) & 63;
        int ys = e >> 9;               // 0..2
        int ysrc = min(max(k - 1 + ys, 0), 63);
        uint4 raw = *(const uint4*)&ffeat[(size_t)(b * LL + ysrc * 64 + xs) * CDIM + ct * 64 + cg * 8];
        float* dst = &ft[ys][cg * 8][xs];
        dst[0]   = b2f((ushort)(raw.x & 0xffff)); dst[65]  = b2f((ushort)(raw.x >> 16));
        dst[130] = b2f((ushort)(raw.y & 0xffff)); dst[195] = b2f((ushort)(raw.y >> 16));
        dst[260] = b2f((ushort)(raw.z & 0xffff)); dst[325] = b2f((ushort)(raw.z >> 16));
        dst[390] = b2f((ushort)(raw.w & 0xffff)); dst[455] = b2f((ushort)(raw.w >> 16));
    }
    __syncthreads();
    int x = tid & 127;
    int half = tid >> 7;
    int y = 2 * k + half;
    int ysA, ysB; float wyA, wyB;
    if (half == 0) { ysA = 0; ysB = 1; wyA = 0.25f; wyB = 0.75f; }
    else           { ysA = 1; ysB = 2; wyA = 0.75f; wyB = 0.25f; }
    int x0; float wx1;
    if ((x & 1) == 0) { x0 = x / 2 - 1; wx1 = 0.75f; }
    else              { x0 = x / 2;     wx1 = 0.25f; }
    int x0c = max(x0, 0);
    int x1c = min(x0 + 1, 63);
    float wx0 = 1.0f - wx1;
    for (int cc = 0; cc < 64; ++cc) {
        float rA = wx0 * ft[ysA][cc][x0c] + wx1 * ft[ysA][cc][x1c];
        float rB = wx0 * ft[ysB][cc][x0c] + wx1 * ft[ysB][cc][x1c];
        float val = wyA * rA + wyB * rB;
        size_t oidx = ((size_t)(b * 256 + ct * 64 + cc) * 128 + y) * 128 + x;
        out[oidx] = val * a3[oidx];
    }
}

// ---------------------------------------------------------------------------
extern "C" void kernel_launch(void* const* d_in, const int* in_sizes, int n_in,
                              void* d_out, int out_size, void* d_ws, size_t ws_size,
                              hipStream_t stream)
{
    const float* a3     = (const float*)d_in[0];
    const float* a4     = (const float*)d_in[1];
    const float* q_w    = (const float*)d_in[2];
    const float* q_b    = (const float*)d_in[3];
    const float* q_ln_g = (const float*)d_in[4];
    const float* q_ln_b = (const float*)d_in[5];
    const float* k_w    = (const float*)d_in[6];
    const float* k_b    = (const float*)d_in[7];
    const float* k_ln_g = (const float*)d_in[8];
    const float* k_ln_b = (const float*)d_in[9];
    const float* v_w    = (const float*)d_in[10];
    const float* v_b    = (const float*)d_in[11];
    const float* out_w  = (const float*)d_in[12];
    const float* out_b  = (const float*)d_in[13];
    const float* lin1_w = (const float*)d_in[14];
    const float* lin1_b = (const float*)d_in[15];
    const float* lin2_w = (const float*)d_in[16];
    const float* lin2_b = (const float*)d_in[17];
    const float* n1_g   = (const float*)d_in[18];
    const float* n1_b   = (const float*)d_in[19];
    const float* n2_g   = (const float*)d_in[20];
    const float* n2_b   = (const float*)d_in[21];
    float* out = (float*)d_out;
    char* base = (char*)d_ws;

    const size_t MiB = 1024 * 1024;
    float*  pos      = (float*)(base);                       // 4 MiB
    float*  snc      = (float*)(base + 4 * MiB);             // 32 KiB
    ushort* wqT      = (ushort*)(base + 4 * MiB + 64 * 1024);
    ushort* wkT      = wqT + 256 * 256;
    ushort* wvT      = wkT + 256 * 256;
    ushort* woT      = wvT + 256 * 256;
    ushort* w1T      = woT + 256 * 256;       // [1024][256]
    ushort* w2T      = w1T + 1024 * 256;      // [256][1024]
    ushort* residual = (ushort*)(base + 6 * MiB);            // 32 MiB (ffeat reuses)
    ushort* x3b      = (ushort*)(base + 38 * MiB);           // 32 MiB (attnb reuses)
    ushort* x4b      = (ushort*)(base + 70 * MiB);           // 32 MiB (res2b reuses)
    ushort* Qb       = (ushort*)(base + 102 * MiB);
    ushort* Kb       = (ushort*)(base + 134 * MiB);
    ushort* Vb       = (ushort*)(base + 166 * MiB);
    float*  kvp      = (float*)(base + 198 * MiB);           // 8 MiB
    float*  ksglob   = (float*)(base + 206 * MiB);           // 32 KiB
    ushort* attnb    = x3b;
    ushort* res2b    = x4b;
    ushort* ffeat    = residual;

    prep_kernel<<<1793, 256, 0, stream>>>(pos, snc, q_w, k_w, v_w, out_w, lin1_w, lin2_w,
                                          wqT, wkT, wvT, woT, w1T, w2T, ksglob);
    pool_x4_kernel<<<dim3(64, 4, 32), 256, 0, stream>>>(a3, a4, residual, x3b, x4b, pos);

    gemm_mfma<true, true, false><<<NROWS / 128, 512, 0, stream>>>(
        x3b, wqT, q_b, q_ln_g, q_ln_b, nullptr, Qb);
    gemm_kv<<<NROWS / 128, 512, 0, stream>>>(
        x4b, wkT, wvT, k_b, k_ln_g, k_ln_b, v_b, snc, ksglob, Kb, Vb);

    kv_kernel<<<dim3(8, 128), 256, 0, stream>>>(Kb, Vb, snc, kvp);
    attn_mfma<<<dim3(16, 8, 16), 256, 0, stream>>>(Qb, kvp, ksglob, snc, attnb);

    // out-proj + LN(n1) + residual -> res2 (bf16)
    gemm_mfma<true, false, true><<<NROWS / 128, 512, 0, stream>>>(
        attnb, woT, out_b, n1_g, n1_b, residual, res2b);
    // fused MLP -> ffeat
    mlp_fused<<<NROWS / 64, 256, 0, stream>>>(
        res2b, w1T, w2T, lin1_b, lin2_b, n2_g, n2_b, ffeat);

    resize_mul_kernel<<<dim3(64, 4, 16), 256, 0, stream>>>(ffeat, a3, out);
}

// Round 16
// 531.932 us; speedup vs baseline: 1.0711x; 1.0711x over previous
//
#include <hip/hip_runtime.h>
#include <hip/hip_bf16.h>
#include <math.h>

#define HEADS 8
#define LL 4096
#define CDIM 256
#define BATCH 16
#define NROWS (BATCH*LL)

typedef __attribute__((ext_vector_type(8))) __bf16 bf16x8;
typedef __attribute__((ext_vector_type(4))) __bf16 bf16x4;
typedef __attribute__((ext_vector_type(4))) float f32x4;

__device__ inline float b2f(ushort u) {
    union { unsigned u; float f; } v; v.u = ((unsigned)u) << 16; return v.f;
}
__device__ inline ushort f2b(float f) {
    union { float f; unsigned u; } v; v.f = f;
    unsigned r = (v.u + 0x7FFF + ((v.u >> 16) & 1)) >> 16;
    return (ushort)r;
}
__device__ inline void gload16(const void* g, void* l) {
    __builtin_amdgcn_global_load_lds(
        (const __attribute__((address_space(1))) unsigned int*)g,
        (__attribute__((address_space(3))) unsigned int*)l, 16, 0, 0);
}
// tanh-form GELU (max ~1e-3 abs error vs erf form; below h1 bf16 noise)
__device__ inline float fast_gelu(float v) {
    float u = 0.7978845608028654f * v * (1.0f + 0.044715f * v * v);
    float e = exp2f(u * 2.885390081777927f);   // e^{2u}
    float t = 1.0f - 2.0f / (e + 1.0f);
    return 0.5f * v * (1.0f + t);
}

// ---------------------------------------------------------------------------
// Fused prep: pos/snc tables (blocks 0..1023), 6 weight transposes (1024..1791),
// ksglob zero (block 1792).
__global__ __launch_bounds__(256) void prep_kernel(
    float* __restrict__ pos, float* __restrict__ snc,
    const float* __restrict__ q_w, const float* __restrict__ k_w,
    const float* __restrict__ v_w, const float* __restrict__ o_w,
    const float* __restrict__ w1, const float* __restrict__ w2,
    ushort* __restrict__ wqT, ushort* __restrict__ wkT,
    ushort* __restrict__ wvT, ushort* __restrict__ woT,
    ushort* __restrict__ w1T, ushort* __restrict__ w2T,
    float* __restrict__ ksglob)
{
    __shared__ float t[32][33];
    int bid = blockIdx.x;
    int tid = threadIdx.x;
    if (bid == 1792) {
        for (int i = tid; i < BATCH * 2 * 256; i += 256) ksglob[i] = 0.0f;
        return;
    }
    if (bid < 1024) {
        int c = tid;
        int k = c & 63;
        float omega = expf(-(float)k * (9.210340371976184f / 64.0f));  // ln(10000)/64
        #pragma unroll
        for (int i = 0; i < 4; ++i) {
            int l = bid * 4 + i;
            int y = l >> 6, x = l & 63;
            float coord = (c < 128) ? (float)y : (float)x;
            float ang = coord * omega;
            float val = ((c & 127) < 64) ? sinf(ang) : cosf(ang);
            pos[l * CDIM + c] = val;
            if (c < 2) {
                float wi = 1.5707963267948966f * (float)(l + 1) / (float)LL;
                snc[l * 2 + c] = (c == 0) ? sinf(wi) : cosf(wi);
            }
        }
        return;
    }
    int id = bid - 1024;
    const float* W; ushort* Wt; int K, N, kb, nb;
    if (id < 64)       { W = q_w; Wt = wqT; K = 256;  N = 256;  kb = (id & 7) * 32;  nb = (id >> 3) * 32; }
    else if (id < 128) { id -= 64;  W = k_w; Wt = wkT; K = 256;  N = 256;  kb = (id & 7) * 32;  nb = (id >> 3) * 32; }
    else if (id < 192) { id -= 128; W = v_w; Wt = wvT; K = 256;  N = 256;  kb = (id & 7) * 32;  nb = (id >> 3) * 32; }
    else if (id < 256) { id -= 192; W = o_w; Wt = woT; K = 256;  N = 256;  kb = (id & 7) * 32;  nb = (id >> 3) * 32; }
    else if (id < 512) { id -= 256; W = w1;  Wt = w1T; K = 256;  N = 1024; kb = (id & 7) * 32;  nb = (id >> 3) * 32; }
    else               { id -= 512; W = w2;  Wt = w2T; K = 1024; N = 256;  kb = (id & 31) * 32; nb = (id >> 5) * 32; }
    int x = tid & 31, y = tid >> 5;
    #pragma unroll
    for (int i = 0; i < 4; ++i)
        t[y + i * 8][x] = W[(size_t)(kb + y + i * 8) * N + nb + x];
    __syncthreads();
    #pragma unroll
    for (int i = 0; i < 4; ++i) {
        int n = y + i * 8;
        Wt[(size_t)(nb + n) * K + kb + x] = f2b(t[x][n]);
    }
}

// ---------------------------------------------------------------------------
// Merged: z<16 -> a3 avgpool2 -> residual bf16 + x3 bf16 (+pos)
//         z>=16 -> a4 transpose -> x4 bf16 (+pos)
__global__ __launch_bounds__(256) void pool_x4_kernel(
    const float* __restrict__ a3, const float* __restrict__ a4,
    ushort* __restrict__ residual, ushort* __restrict__ x3b,
    ushort* __restrict__ x4b, const float* __restrict__ pos)
{
    __shared__ float raw[64][128];
    __shared__ float pooled[64][65];
    int tid = threadIdx.x;
    int ct = blockIdx.y;
    if (blockIdx.z < 16) {
        int i = blockIdx.x, b = blockIdx.z;
        #pragma unroll
        for (int it = 0; it < 8; ++it) {
            int lin = (it * 256 + tid) * 4;
            int x = lin & 127;
            int cc = lin >> 7;
            size_t base = ((size_t)(b * 256 + ct * 64 + cc) * 128 + 2 * i) * 128 + x;
            float4 v0 = *(const float4*)&a3[base];
            float4 v1 = *(const float4*)&a3[base + 128];
            float4 s = make_float4(v0.x + v1.x, v0.y + v1.y, v0.z + v1.z, v0.w + v1.w);
            *(float4*)&raw[cc][x] = s;
        }
        __syncthreads();
        #pragma unroll
        for (int it = 0; it < 16; ++it) {
            int idx = it * 256 + tid;
            int j = idx & 63, cc = idx >> 6;
            pooled[cc][j] = 0.25f * (raw[cc][2 * j] + raw[cc][2 * j + 1]);
        }
        __syncthreads();
        #pragma unroll
        for (int it = 0; it < 16; ++it) {
            int cc = tid & 63;
            int jj = (tid >> 6) + it * 4;
            float val = pooled[cc][jj];
            int l = i * 64 + jj;
            int c = ct * 64 + cc;
            size_t o = (size_t)(b * LL + l) * CDIM + c;
            residual[o] = f2b(val);
            x3b[o] = f2b(val + pos[l * CDIM + c]);
        }
    } else {
        int y = blockIdx.x, b = blockIdx.z - 16;
        #pragma unroll
        for (int it = 0; it < 16; ++it) {
            int idx = it * 256 + tid;
            int x = idx & 63, cc = idx >> 6;
            pooled[cc][x] = a4[((size_t)(b * 256 + ct * 64 + cc) * 64 + y) * 64 + x];
        }
        __syncthreads();
        #pragma unroll
        for (int it = 0; it < 16; ++it) {
            int cc = tid & 63;
            int xx = (tid >> 6) + it * 4;
            int l = y * 64 + xx, c = ct * 64 + cc;
            x4b[(size_t)(b * LL + l) * CDIM + c] = f2b(pooled[cc][xx] + pos[l * CDIM + c]);
        }
    }
}

// ---------------------------------------------------------------------------
// MFMA GEMM (K=256, cols=256): out = epilogue(A @ Wt^T + bias) [+ res].
// 128 rows x 256 cols per block, 512 thr = 8 waves (2 row x 4 col), 64x64/wave.
// 2-phase double-buffered, 1 barrier/step.
template<bool DO_LN, bool DO_RELU, bool DO_RES>
__global__ __launch_bounds__(512, 4) void gemm_mfma(
    const ushort* __restrict__ A, const ushort* __restrict__ Wt,
    const float* __restrict__ bias, const float* __restrict__ gam_,
    const float* __restrict__ bet_, const ushort* __restrict__ res,
    ushort* __restrict__ outb)
{
    __shared__ ushort As[2][128 * 32];   // 8 KB each
    __shared__ ushort Bs[2][256 * 32];   // 16 KB each
    __shared__ float redS[128][4];
    __shared__ float redQ[128][4];
    __shared__ float2 mustd[128];

    const int tid = threadIdx.x;
    const int lane = tid & 63;
    const int wv = tid >> 6;     // 0..7
    const int wr = wv >> 2;      // 0..1
    const int wc = wv & 3;       // 0..3
    const int wvu = __builtin_amdgcn_readfirstlane(wv);
    const int row0 = blockIdx.x * 128;

    const int sr = tid >> 2;                      // 0..127
    const int sg = (tid & 3) ^ ((sr >> 1) & 3);   // swizzled source k-group
    const ushort* aSrc = A + (size_t)(row0 + sr) * 256 + sg * 8;
    const ushort* bSrc0 = Wt + (size_t)sr * 256 + sg * 8;
    const ushort* bSrc1 = Wt + (size_t)(128 + sr) * 256 + sg * 8;

    const int frSlot = (lane >> 4) ^ (((lane & 15) >> 1) & 3);

    f32x4 acc[4][4] = {};
    gload16(aSrc, (char*)&As[0][0] + wvu * 1024);
    gload16(bSrc0, (char*)&Bs[0][0] + wvu * 1024);
    gload16(bSrc1, (char*)&Bs[0][0] + 8192 + wvu * 1024);
    __syncthreads();

    int cur = 0;
    for (int t = 0; t < 8; ++t) {
        if (t < 7) {
            gload16(aSrc + (t + 1) * 32, (char*)&As[cur ^ 1][0] + wvu * 1024);
            gload16(bSrc0 + (t + 1) * 32, (char*)&Bs[cur ^ 1][0] + wvu * 1024);
            gload16(bSrc1 + (t + 1) * 32, (char*)&Bs[cur ^ 1][0] + 8192 + wvu * 1024);
        }
        bf16x8 af[4], bfr[4];
        #pragma unroll
        for (int f = 0; f < 4; ++f) {
            int r = wr * 64 + f * 16 + (lane & 15);
            af[f] = *(const bf16x8*)&As[cur][r * 32 + frSlot * 8];
            int c = wc * 64 + f * 16 + (lane & 15);
            bfr[f] = *(const bf16x8*)&Bs[cur][c * 32 + frSlot * 8];
        }
        __builtin_amdgcn_s_setprio(1);
        #pragma unroll
        for (int fi = 0; fi < 4; ++fi)
            #pragma unroll
            for (int fj = 0; fj < 4; ++fj)
                acc[fi][fj] = __builtin_amdgcn_mfma_f32_16x16x32_bf16(
                    af[fi], bfr[fj], acc[fi][fj], 0, 0, 0);
        __builtin_amdgcn_s_setprio(0);
        __syncthreads();
        cur ^= 1;
    }

    const int cl = lane & 15;
    const int rg = lane >> 4;
    float bia[4], gmv[4], btv[4];
    #pragma unroll
    for (int fj = 0; fj < 4; ++fj) {
        int col = wc * 64 + fj * 16 + cl;
        bia[fj] = bias[col];
        if constexpr (DO_LN) { gmv[fj] = gam_[col]; btv[fj] = bet_[col]; }
    }
    #pragma unroll
    for (int fi = 0; fi < 4; ++fi)
        #pragma unroll
        for (int fj = 0; fj < 4; ++fj)
            #pragma unroll
            for (int j = 0; j < 4; ++j)
                acc[fi][fj][j] += bia[fj];

    if constexpr (DO_LN) {
        #pragma unroll
        for (int fi = 0; fi < 4; ++fi)
            #pragma unroll
            for (int j = 0; j < 4; ++j) {
                float s = acc[fi][0][j] + acc[fi][1][j] + acc[fi][2][j] + acc[fi][3][j];
                float q = acc[fi][0][j] * acc[fi][0][j] + acc[fi][1][j] * acc[fi][1][j]
                        + acc[fi][2][j] * acc[fi][2][j] + acc[fi][3][j] * acc[fi][3][j];
                #pragma unroll
                for (int m = 1; m <= 8; m <<= 1) {
                    s += __shfl_xor(s, m, 64);
                    q += __shfl_xor(q, m, 64);
                }
                if (cl == 0) {
                    int tr = wr * 64 + fi * 16 + rg * 4 + j;
                    redS[tr][wc] = s; redQ[tr][wc] = q;
                }
            }
        __syncthreads();
        if (tid < 128) {
            float s = redS[tid][0] + redS[tid][1] + redS[tid][2] + redS[tid][3];
            float q = redQ[tid][0] + redQ[tid][1] + redQ[tid][2] + redQ[tid][3];
            float mu = s * (1.0f / 256.0f);
            float var = q * (1.0f / 256.0f) - mu * mu;
            mustd[tid] = make_float2(mu, rsqrtf(var + 1e-5f));
        }
        __syncthreads();
        #pragma unroll
        for (int fi = 0; fi < 4; ++fi)
            #pragma unroll
            for (int j = 0; j < 4; ++j) {
                float2 ms = mustd[wr * 64 + fi * 16 + rg * 4 + j];
                #pragma unroll
                for (int fj = 0; fj < 4; ++fj)
                    acc[fi][fj][j] = (acc[fi][fj][j] - ms.x) * ms.y * gmv[fj] + btv[fj];
            }
    }
    if constexpr (DO_RELU) {
        #pragma unroll
        for (int fi = 0; fi < 4; ++fi)
            #pragma unroll
            for (int fj = 0; fj < 4; ++fj)
                #pragma unroll
                for (int j = 0; j < 4; ++j)
                    acc[fi][fj][j] = fmaxf(acc[fi][fj][j], 0.0f);
    }
    #pragma unroll
    for (int fi = 0; fi < 4; ++fi)
        #pragma unroll
        for (int j = 0; j < 4; ++j) {
            size_t row = row0 + wr * 64 + fi * 16 + rg * 4 + j;
            size_t rbase = row * 256 + wc * 64 + cl;
            #pragma unroll
            for (int fj = 0; fj < 4; ++fj) {
                float v = acc[fi][fj][j];
                if constexpr (DO_RES) v += b2f(res[rbase + fj * 16]);
                outb[rbase + fj * 16] = f2b(v);
            }
        }
}

// ---------------------------------------------------------------------------
// Fused K+V GEMM (128 rows, 512 thr, dbuf): K = relu(LN(x4@k_w+k_b)), V = x4@v_w+v_b.
// Reduction scratch aliased into As (dead after K-loop) -> 80 KB LDS -> 2 blocks/CU.
__global__ __launch_bounds__(512, 2) void gemm_kv(
    const ushort* __restrict__ A, const ushort* __restrict__ wkT,
    const ushort* __restrict__ wvT, const float* __restrict__ k_b,
    const float* __restrict__ k_g, const float* __restrict__ k_beta,
    const float* __restrict__ v_b, const float* __restrict__ snc,
    float* __restrict__ ksglob, ushort* __restrict__ Kb, ushort* __restrict__ Vb)
{
    __shared__ ushort As[2][128 * 32];    // 8 KB each; epilogue reuses as scratch
    __shared__ ushort BsK[2][256 * 32];   // 16 KB each
    __shared__ ushort BsV[2][256 * 32];
    float*  redS  = (float*)&As[0][0];        // [128][4]
    float*  redQ  = redS + 512;
    float2* mustd = (float2*)(redQ + 512);

    const int tid = threadIdx.x;
    const int lane = tid & 63;
    const int wv = tid >> 6;
    const int wr = wv >> 2;
    const int wc = wv & 3;
    const int wvu = __builtin_amdgcn_readfirstlane(wv);
    const int row0 = blockIdx.x * 128;

    const int sr = tid >> 2;
    const int sg = (tid & 3) ^ ((sr >> 1) & 3);
    const ushort* aSrc = A + (size_t)(row0 + sr) * 256 + sg * 8;
    const ushort* bkSrc0 = wkT + (size_t)sr * 256 + sg * 8;
    const ushort* bkSrc1 = wkT + (size_t)(128 + sr) * 256 + sg * 8;
    const ushort* bvSrc0 = wvT + (size_t)sr * 256 + sg * 8;
    const ushort* bvSrc1 = wvT + (size_t)(128 + sr) * 256 + sg * 8;

    const int frSlot = (lane >> 4) ^ (((lane & 15) >> 1) & 3);

    f32x4 accK[4][4] = {};
    f32x4 accV[4][4] = {};
    gload16(aSrc, (char*)&As[0][0] + wvu * 1024);
    gload16(bkSrc0, (char*)&BsK[0][0] + wvu * 1024);
    gload16(bkSrc1, (char*)&BsK[0][0] + 8192 + wvu * 1024);
    gload16(bvSrc0, (char*)&BsV[0][0] + wvu * 1024);
    gload16(bvSrc1, (char*)&BsV[0][0] + 8192 + wvu * 1024);
    __syncthreads();

    int cur = 0;
    for (int t = 0; t < 8; ++t) {
        if (t < 7) {
            gload16(aSrc + (t + 1) * 32, (char*)&As[cur ^ 1][0] + wvu * 1024);
            gload16(bkSrc0 + (t + 1) * 32, (char*)&BsK[cur ^ 1][0] + wvu * 1024);
            gload16(bkSrc1 + (t + 1) * 32, (char*)&BsK[cur ^ 1][0] + 8192 + wvu * 1024);
            gload16(bvSrc0 + (t + 1) * 32, (char*)&BsV[cur ^ 1][0] + wvu * 1024);
            gload16(bvSrc1 + (t + 1) * 32, (char*)&BsV[cur ^ 1][0] + 8192 + wvu * 1024);
        }
        bf16x8 af[4], bk[4], bv[4];
        #pragma unroll
        for (int f = 0; f < 4; ++f) {
            int r = wr * 64 + f * 16 + (lane & 15);
            af[f] = *(const bf16x8*)&As[cur][r * 32 + frSlot * 8];
            int c = wc * 64 + f * 16 + (lane & 15);
            bk[f] = *(const bf16x8*)&BsK[cur][c * 32 + frSlot * 8];
            bv[f] = *(const bf16x8*)&BsV[cur][c * 32 + frSlot * 8];
        }
        __builtin_amdgcn_s_setprio(1);
        #pragma unroll
        for (int fi = 0; fi < 4; ++fi)
            #pragma unroll
            for (int fj = 0; fj < 4; ++fj) {
                accK[fi][fj] = __builtin_amdgcn_mfma_f32_16x16x32_bf16(
                    af[fi], bk[fj], accK[fi][fj], 0, 0, 0);
                accV[fi][fj] = __builtin_amdgcn_mfma_f32_16x16x32_bf16(
                    af[fi], bv[fj], accV[fi][fj], 0, 0, 0);
            }
        __builtin_amdgcn_s_setprio(0);
        __syncthreads();
        cur ^= 1;
    }

    const int cl = lane & 15;
    const int rg = lane >> 4;
    // ---- V epilogue ----
    #pragma unroll
    for (int fj = 0; fj < 4; ++fj) {
        float bv_ = v_b[wc * 64 + fj * 16 + cl];
        #pragma unroll
        for (int fi = 0; fi < 4; ++fi)
            #pragma unroll
            for (int j = 0; j < 4; ++j)
                accV[fi][fj][j] += bv_;
    }
    #pragma unroll
    for (int fi = 0; fi < 4; ++fi)
        #pragma unroll
        for (int j = 0; j < 4; ++j) {
            size_t rbase = (size_t)(row0 + wr * 64 + fi * 16 + rg * 4 + j) * 256 + wc * 64 + cl;
            #pragma unroll
            for (int fj = 0; fj < 4; ++fj)
                Vb[rbase + fj * 16] = f2b(accV[fi][fj][j]);
        }
    // ---- K epilogue: bias + LN + relu + ksum + store ----
    float bia[4], gmv[4], btv[4];
    #pragma unroll
    for (int fj = 0; fj < 4; ++fj) {
        int col = wc * 64 + fj * 16 + cl;
        bia[fj] = k_b[col]; gmv[fj] = k_g[col]; btv[fj] = k_beta[col];
    }
    #pragma unroll
    for (int fi = 0; fi < 4; ++fi)
        #pragma unroll
        for (int fj = 0; fj < 4; ++fj)
            #pragma unroll
            for (int j = 0; j < 4; ++j)
                accK[fi][fj][j] += bia[fj];
    #pragma unroll
    for (int fi = 0; fi < 4; ++fi)
        #pragma unroll
        for (int j = 0; j < 4; ++j) {
            float s = accK[fi][0][j] + accK[fi][1][j] + accK[fi][2][j] + accK[fi][3][j];
            float q = accK[fi][0][j] * accK[fi][0][j] + accK[fi][1][j] * accK[fi][1][j]
                    + accK[fi][2][j] * accK[fi][2][j] + accK[fi][3][j] * accK[fi][3][j];
            #pragma unroll
            for (int m = 1; m <= 8; m <<= 1) {
                s += __shfl_xor(s, m, 64);
                q += __shfl_xor(q, m, 64);
            }
            if (cl == 0) {
                int tr = wr * 64 + fi * 16 + rg * 4 + j;
                redS[tr * 4 + wc] = s; redQ[tr * 4 + wc] = q;
            }
        }
    __syncthreads();
    if (tid < 128) {
        float s = redS[tid * 4] + redS[tid * 4 + 1] + redS[tid * 4 + 2] + redS[tid * 4 + 3];
        float q = redQ[tid * 4] + redQ[tid * 4 + 1] + redQ[tid * 4 + 2] + redQ[tid * 4 + 3];
        float mu = s * (1.0f / 256.0f);
        float var = q * (1.0f / 256.0f) - mu * mu;
        mustd[tid] = make_float2(mu, rsqrtf(var + 1e-5f));
    }
    __syncthreads();
    float kss[4] = {}, ksc[4] = {};
    #pragma unroll
    for (int fi = 0; fi < 4; ++fi)
        #pragma unroll
        for (int j = 0; j < 4; ++j) {
            int rloc = wr * 64 + fi * 16 + rg * 4 + j;
            float2 ms = mustd[rloc];
            int l = (row0 + rloc) & (LL - 1);
            float sn = snc[l * 2], cs = snc[l * 2 + 1];
            size_t rbase = (size_t)(row0 + rloc) * 256 + wc * 64 + cl;
            #pragma unroll
            for (int fj = 0; fj < 4; ++fj) {
                float v = (accK[fi][fj][j] - ms.x) * ms.y * gmv[fj] + btv[fj];
                v = fmaxf(v, 0.0f);
                Kb[rbase + fj * 16] = f2b(v);
                kss[fj] += sn * v;
                ksc[fj] += cs * v;
            }
        }
    int b = row0 >> 12;
    #pragma unroll
    for (int fj = 0; fj < 4; ++fj) {
        float s = kss[fj], c = ksc[fj];
        s += __shfl_xor(s, 16, 64); s += __shfl_xor(s, 32, 64);
        c += __shfl_xor(c, 16, 64); c += __shfl_xor(c, 32, 64);
        if (rg == 0) {
            int col = wc * 64 + fj * 16 + cl;
            atomicAdd(&ksglob[((size_t)b * 2 + 0) * 256 + col], s);
            atomicAdd(&ksglob[((size_t)b * 2 + 1) * 256 + col], c);
        }
    }
}

// ---------------------------------------------------------------------------
// Fused MLP: out = LN2(gelu(res2@W1+b1)@W2+b2) + res2.
// 64 rows/block, 4 chunks of 256 h1-cols; h1 chunk in LDS as [t][64][36] (padded).
__global__ __launch_bounds__(256, 2) void mlp_fused(
    const ushort* __restrict__ res2, const ushort* __restrict__ w1T,
    const ushort* __restrict__ w2T, const float* __restrict__ b1,
    const float* __restrict__ b2, const float* __restrict__ gam_,
    const float* __restrict__ bet_, ushort* __restrict__ outb)
{
    __shared__ ushort As[2][64 * 32];
    __shared__ ushort Bs[2][256 * 32];
    __shared__ ushort h1c[8 * 64 * 36];   // 36 KB, 72B row stride (odd dword count)
    __shared__ float redS[64][4];
    __shared__ float redQ[64][4];
    __shared__ float2 mustd[64];

    const int tid = threadIdx.x;
    const int lane = tid & 63;
    const int wv = tid >> 6;
    const int wvu = __builtin_amdgcn_readfirstlane(wv);
    const int row0 = blockIdx.x * 64;
    const int sr = tid >> 2;
    const int sg = (tid & 3) ^ ((sr >> 1) & 3);
    const ushort* aSrc = res2 + (size_t)(row0 + sr) * 256 + sg * 8;
    const int frSlot = (lane >> 4) ^ (((lane & 15) >> 1) & 3);
    const int cl = lane & 15;
    const int rg = lane >> 4;

    f32x4 acc2[4][4] = {};
    gload16(aSrc, (char*)&As[0][0] + wvu * 1024);
    #pragma unroll
    for (int j = 0; j < 4; ++j)
        gload16(w1T + (size_t)(j * 64 + sr) * 256 + sg * 8,
                (char*)&Bs[0][0] + j * 4096 + wvu * 1024);
    __syncthreads();
    int cur = 0;

    for (int c = 0; c < 4; ++c) {
        const ushort* b1Src = w1T + (size_t)(c * 256 + sr) * 256 + sg * 8;
        const ushort* b2Src = w2T + (size_t)sr * 1024 + c * 256 + sg * 8;
        f32x4 acc1[4][4] = {};
        // ---- GEMM1 over K=256 (8 steps) ----
        for (int t = 0; t < 8; ++t) {
            if (t < 7) {
                gload16(aSrc + (t + 1) * 32, (char*)&As[cur ^ 1][0] + wvu * 1024);
                #pragma unroll
                for (int j = 0; j < 4; ++j)
                    gload16(b1Src + j * 64 * 256 + (t + 1) * 32,
                            (char*)&Bs[cur ^ 1][0] + j * 4096 + wvu * 1024);
            } else {
                gload16(aSrc, (char*)&As[cur ^ 1][0] + wvu * 1024);
                #pragma unroll
                for (int j = 0; j < 4; ++j)
                    gload16(b2Src + (size_t)j * 64 * 1024,
                            (char*)&Bs[cur ^ 1][0] + j * 4096 + wvu * 1024);
            }
            bf16x8 af[4], bfr[4];
            #pragma unroll
            for (int f = 0; f < 4; ++f) {
                int r = f * 16 + (lane & 15);
                af[f] = *(const bf16x8*)&As[cur][r * 32 + frSlot * 8];
                int cc2 = wv * 64 + f * 16 + (lane & 15);
                bfr[f] = *(const bf16x8*)&Bs[cur][cc2 * 32 + frSlot * 8];
            }
            __builtin_amdgcn_s_setprio(1);
            #pragma unroll
            for (int fi = 0; fi < 4; ++fi)
                #pragma unroll
                for (int fj = 0; fj < 4; ++fj)
                    acc1[fi][fj] = __builtin_amdgcn_mfma_f32_16x16x32_bf16(
                        af[fi], bfr[fj], acc1[fi][fj], 0, 0, 0);
            __builtin_amdgcn_s_setprio(0);
            __syncthreads();
            cur ^= 1;
        }
        // ---- epilogue1: bias + fast gelu -> h1c ----
        float bia1[4];
        #pragma unroll
        for (int fj = 0; fj < 4; ++fj)
            bia1[fj] = b1[c * 256 + wv * 64 + fj * 16 + cl];
        #pragma unroll
        for (int fi = 0; fi < 4; ++fi)
            #pragma unroll
            for (int fj = 0; fj < 4; ++fj) {
                int tch = wv * 2 + (fj >> 1);
                int kk_local = (fj & 1) * 16 + cl;
                #pragma unroll
                for (int j = 0; j < 4; ++j) {
                    float v = acc1[fi][fj][j] + bia1[fj];
                    float g = fast_gelu(v);
                    int row = fi * 16 + rg * 4 + j;
                    h1c[tch * 2304 + row * 36 + kk_local] = f2b(g);
                }
            }
        __syncthreads();
        // ---- GEMM2 over this chunk's K=256 (8 steps) ----
        for (int t = 0; t < 8; ++t) {
            if (t < 7) {
                #pragma unroll
                for (int j = 0; j < 4; ++j)
                    gload16(b2Src + (size_t)j * 64 * 1024 + (t + 1) * 32,
                            (char*)&Bs[cur ^ 1][0] + j * 4096 + wvu * 1024);
            } else {
                int cn = (c < 3) ? c + 1 : 3;
                #pragma unroll
                for (int j = 0; j < 4; ++j)
                    gload16(w1T + (size_t)(cn * 256 + j * 64 + sr) * 256 + sg * 8,
                            (char*)&Bs[cur ^ 1][0] + j * 4096 + wvu * 1024);
            }
            bf16x8 af[4], bfr[4];
            #pragma unroll
            for (int f = 0; f < 4; ++f) {
                int r = f * 16 + (lane & 15);
                int ho = t * 2304 + r * 36 + (lane >> 4) * 8;
                bf16x4 lo = *(const bf16x4*)&h1c[ho];
                bf16x4 hi = *(const bf16x4*)&h1c[ho + 4];
                bf16x8 a_;
                a_[0] = lo[0]; a_[1] = lo[1]; a_[2] = lo[2]; a_[3] = lo[3];
                a_[4] = hi[0]; a_[5] = hi[1]; a_[6] = hi[2]; a_[7] = hi[3];
                af[f] = a_;
                int cc2 = wv * 64 + f * 16 + (lane & 15);
                bfr[f] = *(const bf16x8*)&Bs[cur][cc2 * 32 + frSlot * 8];
            }
            __builtin_amdgcn_s_setprio(1);
            #pragma unroll
            for (int fi = 0; fi < 4; ++fi)
                #pragma unroll
                for (int fj = 0; fj < 4; ++fj)
                    acc2[fi][fj] = __builtin_amdgcn_mfma_f32_16x16x32_bf16(
                        af[fi], bfr[fj], acc2[fi][fj], 0, 0, 0);
            __builtin_amdgcn_s_setprio(0);
            __syncthreads();
            cur ^= 1;
        }
    }
    // ---- epilogue2: + b2, LN(n2), + res2 residual, write bf16 ----
    float bia[4], gmv[4], btv[4];
    #pragma unroll
    for (int fj = 0; fj < 4; ++fj) {
        int col = wv * 64 + fj * 16 + cl;
        bia[fj] = b2[col];
        gmv[fj] = gam_[col];
        btv[fj] = bet_[col];
    }
    #pragma unroll
    for (int fi = 0; fi < 4; ++fi)
        #pragma unroll
        for (int fj = 0; fj < 4; ++fj)
            #pragma unroll
            for (int j = 0; j < 4; ++j)
                acc2[fi][fj][j] += bia[fj];
    #pragma unroll
    for (int fi = 0; fi < 4; ++fi)
        #pragma unroll
        for (int j = 0; j < 4; ++j) {
            float s = acc2[fi][0][j] + acc2[fi][1][j] + acc2[fi][2][j] + acc2[fi][3][j];
            float q = acc2[fi][0][j] * acc2[fi][0][j] + acc2[fi][1][j] * acc2[fi][1][j]
                    + acc2[fi][2][j] * acc2[fi][2][j] + acc2[fi][3][j] * acc2[fi][3][j];
            #pragma unroll
            for (int m = 1; m <= 8; m <<= 1) {
                s += __shfl_xor(s, m, 64);
                q += __shfl_xor(q, m, 64);
            }
            if (cl == 0) { redS[fi * 16 + rg * 4 + j][wv] = s; redQ[fi * 16 + rg * 4 + j][wv] = q; }
        }
    __syncthreads();
    if (tid < 64) {
        float s = redS[tid][0] + redS[tid][1] + redS[tid][2] + redS[tid][3];
        float q = redQ[tid][0] + redQ[tid][1] + redQ[tid][2] + redQ[tid][3];
        float mu = s * (1.0f / 256.0f);
        float var = q * (1.0f / 256.0f) - mu * mu;
        mustd[tid] = make_float2(mu, rsqrtf(var + 1e-5f));
    }
    __syncthreads();
    #pragma unroll
    for (int fi = 0; fi < 4; ++fi)
        #pragma unroll
        for (int j = 0; j < 4; ++j) {
            float2 ms = mustd[fi * 16 + rg * 4 + j];
            size_t row = row0 + fi * 16 + rg * 4 + j;
            size_t rbase = row * 256 + wv * 64 + cl;
            #pragma unroll
            for (int fj = 0; fj < 4; ++fj) {
                float v = (acc2[fi][fj][j] - ms.x) * ms.y * gmv[fj] + btv[fj];
                v += b2f(res2[rbase + fj * 16]);
                outb[rbase + fj * 16] = f2b(v);
            }
        }
}

// ---------------------------------------------------------------------------
// cosFormer stage 1: partial KVs/KVc (32x32) per (b,h,chunk). Stride 2048.
__global__ __launch_bounds__(256) void kv_kernel(
    const ushort* __restrict__ Kmat, const ushort* __restrict__ Vmat,
    const float* __restrict__ snc, float* __restrict__ kvpart)
{
    __shared__ float Kt[64][36];
    __shared__ float Vt[64][36];
    __shared__ float sns[64], css[64];
    int chunk = blockIdx.x;
    int bh = blockIdx.y;
    int b = bh >> 3, h = bh & 7;
    int tid = threadIdx.x;
    int m = tid & 31;
    int d0 = (tid >> 5) * 4;
    float accs[4] = {}, accc[4] = {};
    int l0chunk = chunk * 512;
    int lrow = tid >> 2;
    int lcol = (tid & 3) * 8;
    for (int sub = 0; sub < 8; ++sub) {
        int l0 = l0chunk + sub * 64;
        {
            size_t gbase = (size_t)(b * LL + l0 + lrow) * CDIM + h * 32 + lcol;
            uint4 kr = *(const uint4*)&Kmat[gbase];
            uint4 vr = *(const uint4*)&Vmat[gbase];
            float* kd = &Kt[lrow][lcol];
            float* vd = &Vt[lrow][lcol];
            kd[0] = b2f((ushort)(kr.x & 0xffff)); kd[1] = b2f((ushort)(kr.x >> 16));
            kd[2] = b2f((ushort)(kr.y & 0xffff)); kd[3] = b2f((ushort)(kr.y >> 16));
            kd[4] = b2f((ushort)(kr.z & 0xffff)); kd[5] = b2f((ushort)(kr.z >> 16));
            kd[6] = b2f((ushort)(kr.w & 0xffff)); kd[7] = b2f((ushort)(kr.w >> 16));
            vd[0] = b2f((ushort)(vr.x & 0xffff)); vd[1] = b2f((ushort)(vr.x >> 16));
            vd[2] = b2f((ushort)(vr.y & 0xffff)); vd[3] = b2f((ushort)(vr.y >> 16));
            vd[4] = b2f((ushort)(vr.z & 0xffff)); vd[5] = b2f((ushort)(vr.z >> 16));
            vd[6] = b2f((ushort)(vr.w & 0xffff)); vd[7] = b2f((ushort)(vr.w >> 16));
        }
        if (tid < 64) { sns[tid] = snc[(l0 + tid) * 2]; css[tid] = snc[(l0 + tid) * 2 + 1]; }
        __syncthreads();
        #pragma unroll 4
        for (int lt = 0; lt < 64; ++lt) {
            float v = Vt[lt][m];
            float vs = v * sns[lt];
            float vc = v * css[lt];
            float4 kd4 = *(const float4*)&Kt[lt][d0];
            accs[0] += kd4.x * vs; accc[0] += kd4.x * vc;
            accs[1] += kd4.y * vs; accc[1] += kd4.y * vc;
            accs[2] += kd4.z * vs; accc[2] += kd4.z * vc;
            accs[3] += kd4.w * vs; accc[3] += kd4.w * vc;
        }
        __syncthreads();
    }
    size_t base = (size_t)(bh * 8 + chunk) * 2048;
    #pragma unroll
    for (int i2 = 0; i2 < 4; ++i2) {
        kvpart[base + (d0 + i2) * 32 + m] = accs[i2];
        kvpart[base + 1024 + (d0 + i2) * 32 + m] = accc[i2];
    }
}

// ---------------------------------------------------------------------------
// Reduce chunk partials into per-(b,h) MFMA B-image, hi/lo bf16 split.
__global__ __launch_bounds__(256) void kvred_kernel(
    const float* __restrict__ kvpart, const float* __restrict__ ksglob,
    ushort* __restrict__ Bimg)
{
    int bh = blockIdx.x;
    int b = bh >> 3, h = bh & 7;
    int tid = threadIdx.x;
    for (int e = tid; e < 2560; e += 256) {
        int n = e >> 5;
        int k = e & 31;
        int t = n >> 4, col = n & 15;
        float v = 0.0f;
        if (t < 4) {
            int off = (t >= 2 ? 1024 : 0) + k * 32 + (t & 1) * 16 + col;
            #pragma unroll
            for (int ch = 0; ch < 8; ++ch)
                v += kvpart[(size_t)(bh * 8 + ch) * 2048 + off];
        } else if (col < 2) {
            v = ksglob[((size_t)b * 2 + col) * 256 + h * 32 + k];
        }
        ushort hi = f2b(v);
        ushort lo = f2b(v - b2f(hi));
        Bimg[(size_t)bh * 5120 + n * 32 + k] = hi;
        Bimg[(size_t)bh * 5120 + (80 + n) * 32 + k] = lo;
    }
}

// ---------------------------------------------------------------------------
// attn via MFMA: per (ltile, h, b): 256 rows.
__global__ __launch_bounds__(256, 2) void attn_mfma(
    const ushort* __restrict__ Qmat, const ushort* __restrict__ Bimg,
    const float* __restrict__ snc, ushort* __restrict__ attnOut)
{
    __shared__ ushort Bs[5120];
    int ltile = blockIdx.x, h = blockIdx.y, b = blockIdx.z;
    int bh = b * 8 + h;
    int tid = threadIdx.x;
    int lane = tid & 63;
    int wv = tid >> 6;

    for (int e = tid; e < 640; e += 256)
        *(uint4*)&Bs[e * 8] = *(const uint4*)&Bimg[(size_t)bh * 5120 + e * 8];
    __syncthreads();

    bf16x8 bfr[10];
    #pragma unroll
    for (int tt = 0; tt < 10; ++tt) {
        int row = (tt < 5 ? tt * 16 : 80 + (tt - 5) * 16) + (lane & 15);
        bfr[tt] = *(const bf16x8*)&Bs[row * 32 + (lane >> 4) * 8];
    }
    int lbase = ltile * 256 + wv * 64;
    bf16x8 af[4];
    #pragma unroll
    for (int fi = 0; fi < 4; ++fi) {
        int l = lbase + fi * 16 + (lane & 15);
        af[fi] = *(const bf16x8*)&Qmat[(size_t)(b * LL + l) * CDIM + h * 32 + (lane >> 4) * 8];
    }
    f32x4 acc[4][5] = {};
    __builtin_amdgcn_s_setprio(1);
    #pragma unroll
    for (int fi = 0; fi < 4; ++fi)
        #pragma unroll
        for (int t = 0; t < 5; ++t) {
            acc[fi][t] = __builtin_amdgcn_mfma_f32_16x16x32_bf16(af[fi], bfr[t], acc[fi][t], 0, 0, 0);
            acc[fi][t] = __builtin_amdgcn_mfma_f32_16x16x32_bf16(af[fi], bfr[t + 5], acc[fi][t], 0, 0, 0);
        }
    __builtin_amdgcn_s_setprio(0);

    int zlane = lane & 48;
    int cl = lane & 15;
    #pragma unroll
    for (int fi = 0; fi < 4; ++fi) {
        #pragma unroll
        for (int j = 0; j < 4; ++j) {
            float zraw = acc[fi][4][j];
            float zs = __shfl(zraw, zlane, 64);
            float zc = __shfl(zraw, zlane | 1, 64);
            int l = lbase + fi * 16 + ((lane >> 4) & 3) * 4 + j;
            float sn = snc[l * 2], cs = snc[l * 2 + 1];
            float den = sn * zs + cs * zc;
            float Z = 1.0f / fmaxf(den, 1e-6f);
            float v0 = (sn * acc[fi][0][j] + cs * acc[fi][2][j]) * Z;
            float v1 = (sn * acc[fi][1][j] + cs * acc[fi][3][j]) * Z;
            size_t ob = (size_t)(b * LL + l) * CDIM + h * 32 + cl;
            attnOut[ob] = f2b(v0);
            attnOut[ob + 16] = f2b(v1);
        }
    }
}

// ---------------------------------------------------------------------------
// ffeat bf16 (b,L,256) -> (b,c,64,64) -> bilinear x2 * a3 -> out f32
// Vectorized ffeat loads: uint4 = 8 bf16 per load (6 loads/thread).
__global__ __launch_bounds__(256) void resize_mul_kernel(
    const ushort* __restrict__ ffeat, const float* __restrict__ a3, float* __restrict__ out)
{
    __shared__ float ft[3][64][65];
    int k = blockIdx.x, ct = blockIdx.y, b = blockIdx.z;
    int tid = threadIdx.x;
    #pragma unroll
    for (int it = 0; it < 6; ++it) {
        int e = it * 256 + tid;        // 0..1535
        int cg = e & 7;                // col-group of 8 bf16
        int xs = (e >> 3) & 63;
        int ys = e >> 9;               // 0..2
        int ysrc = min(max(k - 1 + ys, 0), 63);
        uint4 raw = *(const uint4*)&ffeat[(size_t)(b * LL + ysrc * 64 + xs) * CDIM + ct * 64 + cg * 8];
        float* dst = &ft[ys][cg * 8][xs];
        dst[0]   = b2f((ushort)(raw.x & 0xffff)); dst[65]  = b2f((ushort)(raw.x >> 16));
        dst[130] = b2f((ushort)(raw.y & 0xffff)); dst[195] = b2f((ushort)(raw.y >> 16));
        dst[260] = b2f((ushort)(raw.z & 0xffff)); dst[325] = b2f((ushort)(raw.z >> 16));
        dst[390] = b2f((ushort)(raw.w & 0xffff)); dst[455] = b2f((ushort)(raw.w >> 16));
    }
    __syncthreads();
    int x = tid & 127;
    int half = tid >> 7;
    int y = 2 * k + half;
    int ysA, ysB; float wyA, wyB;
    if (half == 0) { ysA = 0; ysB = 1; wyA = 0.25f; wyB = 0.75f; }
    else           { ysA = 1; ysB = 2; wyA = 0.75f; wyB = 0.25f; }
    int x0; float wx1;
    if ((x & 1) == 0) { x0 = x / 2 - 1; wx1 = 0.75f; }
    else              { x0 = x / 2;     wx1 = 0.25f; }
    int x0c = max(x0, 0);
    int x1c = min(x0 + 1, 63);
    float wx0 = 1.0f - wx1;
    for (int cc = 0; cc < 64; ++cc) {
        float rA = wx0 * ft[ysA][cc][x0c] + wx1 * ft[ysA][cc][x1c];
        float rB = wx0 * ft[ysB][cc][x0c] + wx1 * ft[ysB][cc][x1c];
        float val = wyA * rA + wyB * rB;
        size_t oidx = ((size_t)(b * 256 + ct * 64 + cc) * 128 + y) * 128 + x;
        out[oidx] = val * a3[oidx];
    }
}

// ---------------------------------------------------------------------------
extern "C" void kernel_launch(void* const* d_in, const int* in_sizes, int n_in,
                              void* d_out, int out_size, void* d_ws, size_t ws_size,
                              hipStream_t stream)
{
    const float* a3     = (const float*)d_in[0];
    const float* a4     = (const float*)d_in[1];
    const float* q_w    = (const float*)d_in[2];
    const float* q_b    = (const float*)d_in[3];
    const float* q_ln_g = (const float*)d_in[4];
    const float* q_ln_b = (const float*)d_in[5];
    const float* k_w    = (const float*)d_in[6];
    const float* k_b    = (const float*)d_in[7];
    const float* k_ln_g = (const float*)d_in[8];
    const float* k_ln_b = (const float*)d_in[9];
    const float* v_w    = (const float*)d_in[10];
    const float* v_b    = (const float*)d_in[11];
    const float* out_w  = (const float*)d_in[12];
    const float* out_b  = (const float*)d_in[13];
    const float* lin1_w = (const float*)d_in[14];
    const float* lin1_b = (const float*)d_in[15];
    const float* lin2_w = (const float*)d_in[16];
    const float* lin2_b = (const float*)d_in[17];
    const float* n1_g   = (const float*)d_in[18];
    const float* n1_b   = (const float*)d_in[19];
    const float* n2_g   = (const float*)d_in[20];
    const float* n2_b   = (const float*)d_in[21];
    float* out = (float*)d_out;
    char* base = (char*)d_ws;

    const size_t MiB = 1024 * 1024;
    float*  pos      = (float*)(base);                       // 4 MiB
    float*  snc      = (float*)(base + 4 * MiB);             // 32 KiB
    ushort* wqT      = (ushort*)(base + 4 * MiB + 64 * 1024);
    ushort* wkT      = wqT + 256 * 256;
    ushort* wvT      = wkT + 256 * 256;
    ushort* woT      = wvT + 256 * 256;
    ushort* w1T      = woT + 256 * 256;       // [1024][256]
    ushort* w2T      = w1T + 1024 * 256;      // [256][1024]
    ushort* residual = (ushort*)(base + 6 * MiB);            // 32 MiB (ffeat reuses)
    ushort* x3b      = (ushort*)(base + 38 * MiB);           // 32 MiB (attnb reuses)
    ushort* x4b      = (ushort*)(base + 70 * MiB);           // 32 MiB (res2b reuses)
    ushort* Qb       = (ushort*)(base + 102 * MiB);
    ushort* Kb       = (ushort*)(base + 134 * MiB);
    ushort* Vb       = (ushort*)(base + 166 * MiB);
    float*  kvp      = (float*)(base + 198 * MiB);           // 8 MiB
    float*  ksglob   = (float*)(base + 206 * MiB);           // 32 KiB
    ushort* Bimg     = (ushort*)(base + 207 * MiB);          // 1.25 MiB
    ushort* attnb    = x3b;
    ushort* res2b    = x4b;
    ushort* ffeat    = residual;

    prep_kernel<<<1793, 256, 0, stream>>>(pos, snc, q_w, k_w, v_w, out_w, lin1_w, lin2_w,
                                          wqT, wkT, wvT, woT, w1T, w2T, ksglob);
    pool_x4_kernel<<<dim3(64, 4, 32), 256, 0, stream>>>(a3, a4, residual, x3b, x4b, pos);

    gemm_mfma<true, true, false><<<NROWS / 128, 512, 0, stream>>>(
        x3b, wqT, q_b, q_ln_g, q_ln_b, nullptr, Qb);
    gemm_kv<<<NROWS / 128, 512, 0, stream>>>(
        x4b, wkT, wvT, k_b, k_ln_g, k_ln_b, v_b, snc, ksglob, Kb, Vb);

    kv_kernel<<<dim3(8, 128), 256, 0, stream>>>(Kb, Vb, snc, kvp);
    kvred_kernel<<<128, 256, 0, stream>>>(kvp, ksglob, Bimg);
    attn_mfma<<<dim3(16, 8, 16), 256, 0, stream>>>(Qb, Bimg, snc, attnb);

    // out-proj + LN(n1) + residual -> res2 (bf16)
    gemm_mfma<true, false, true><<<NROWS / 128, 512, 0, stream>>>(
        attnb, woT, out_b, n1_g, n1_b, residual, res2b);
    // fused MLP -> ffeat
    mlp_fused<<<NROWS / 64, 256, 0, stream>>>(
        res2b, w1T, w2T, lin1_b, lin2_b, n2_g, n2_b, ffeat);

    resize_mul_kernel<<<dim3(64, 4, 16), 256, 0, stream>>>(ffeat, a3, out);
}

// Round 17
// 528.222 us; speedup vs baseline: 1.0787x; 1.0070x over previous
//
#include <hip/hip_runtime.h>
#include <hip/hip_bf16.h>
#include <math.h>

#define HEADS 8
#define LL 4096
#define CDIM 256
#define BATCH 16
#define NROWS (BATCH*LL)

typedef __attribute__((ext_vector_type(8))) __bf16 bf16x8;
typedef __attribute__((ext_vector_type(4))) __bf16 bf16x4;
typedef __attribute__((ext_vector_type(4))) float f32x4;

__device__ inline float b2f(ushort u) {
    union { unsigned u; float f; } v; v.u = ((unsigned)u) << 16; return v.f;
}
__device__ inline ushort f2b(float f) {
    union { float f; unsigned u; } v; v.f = f;
    unsigned r = (v.u + 0x7FFF + ((v.u >> 16) & 1)) >> 16;
    return (ushort)r;
}
__device__ inline void gload16(const void* g, void* l) {
    __builtin_amdgcn_global_load_lds(
        (const __attribute__((address_space(1))) unsigned int*)g,
        (__attribute__((address_space(3))) unsigned int*)l, 16, 0, 0);
}
// tanh-form GELU (max ~1e-3 abs error vs erf form; below h1 bf16 noise)
__device__ inline float fast_gelu(float v) {
    float u = 0.7978845608028654f * v * (1.0f + 0.044715f * v * v);
    float e = exp2f(u * 2.885390081777927f);   // e^{2u}
    float t = 1.0f - 2.0f / (e + 1.0f);
    return 0.5f * v * (1.0f + t);
}

// ---------------------------------------------------------------------------
// Fused prep: pos/snc tables (blocks 0..1023), 6 weight transposes (1024..1791),
// ksglob zero (block 1792).
__global__ __launch_bounds__(256) void prep_kernel(
    float* __restrict__ pos, float* __restrict__ snc,
    const float* __restrict__ q_w, const float* __restrict__ k_w,
    const float* __restrict__ v_w, const float* __restrict__ o_w,
    const float* __restrict__ w1, const float* __restrict__ w2,
    ushort* __restrict__ wqT, ushort* __restrict__ wkT,
    ushort* __restrict__ wvT, ushort* __restrict__ woT,
    ushort* __restrict__ w1T, ushort* __restrict__ w2T,
    float* __restrict__ ksglob)
{
    __shared__ float t[32][33];
    int bid = blockIdx.x;
    int tid = threadIdx.x;
    if (bid == 1792) {
        for (int i = tid; i < BATCH * 2 * 256; i += 256) ksglob[i] = 0.0f;
        return;
    }
    if (bid < 1024) {
        int c = tid;
        int k = c & 63;
        float omega = expf(-(float)k * (9.210340371976184f / 64.0f));  // ln(10000)/64
        #pragma unroll
        for (int i = 0; i < 4; ++i) {
            int l = bid * 4 + i;
            int y = l >> 6, x = l & 63;
            float coord = (c < 128) ? (float)y : (float)x;
            float ang = coord * omega;
            float val = ((c & 127) < 64) ? sinf(ang) : cosf(ang);
            pos[l * CDIM + c] = val;
            if (c < 2) {
                float wi = 1.5707963267948966f * (float)(l + 1) / (float)LL;
                snc[l * 2 + c] = (c == 0) ? sinf(wi) : cosf(wi);
            }
        }
        return;
    }
    int id = bid - 1024;
    const float* W; ushort* Wt; int K, N, kb, nb;
    if (id < 64)       { W = q_w; Wt = wqT; K = 256;  N = 256;  kb = (id & 7) * 32;  nb = (id >> 3) * 32; }
    else if (id < 128) { id -= 64;  W = k_w; Wt = wkT; K = 256;  N = 256;  kb = (id & 7) * 32;  nb = (id >> 3) * 32; }
    else if (id < 192) { id -= 128; W = v_w; Wt = wvT; K = 256;  N = 256;  kb = (id & 7) * 32;  nb = (id >> 3) * 32; }
    else if (id < 256) { id -= 192; W = o_w; Wt = woT; K = 256;  N = 256;  kb = (id & 7) * 32;  nb = (id >> 3) * 32; }
    else if (id < 512) { id -= 256; W = w1;  Wt = w1T; K = 256;  N = 1024; kb = (id & 7) * 32;  nb = (id >> 3) * 32; }
    else               { id -= 512; W = w2;  Wt = w2T; K = 1024; N = 256;  kb = (id & 31) * 32; nb = (id >> 5) * 32; }
    int x = tid & 31, y = tid >> 5;
    #pragma unroll
    for (int i = 0; i < 4; ++i)
        t[y + i * 8][x] = W[(size_t)(kb + y + i * 8) * N + nb + x];
    __syncthreads();
    #pragma unroll
    for (int i = 0; i < 4; ++i) {
        int n = y + i * 8;
        Wt[(size_t)(nb + n) * K + kb + x] = f2b(t[x][n]);
    }
}

// ---------------------------------------------------------------------------
// Merged: z<16 -> a3 avgpool2 -> residual bf16 + x3 bf16 (+pos)
//         z>=16 -> a4 transpose -> x4 bf16 (+pos)
__global__ __launch_bounds__(256) void pool_x4_kernel(
    const float* __restrict__ a3, const float* __restrict__ a4,
    ushort* __restrict__ residual, ushort* __restrict__ x3b,
    ushort* __restrict__ x4b, const float* __restrict__ pos)
{
    __shared__ float raw[64][128];
    __shared__ float pooled[64][65];
    int tid = threadIdx.x;
    int ct = blockIdx.y;
    if (blockIdx.z < 16) {
        int i = blockIdx.x, b = blockIdx.z;
        #pragma unroll
        for (int it = 0; it < 8; ++it) {
            int lin = (it * 256 + tid) * 4;
            int x = lin & 127;
            int cc = lin >> 7;
            size_t base = ((size_t)(b * 256 + ct * 64 + cc) * 128 + 2 * i) * 128 + x;
            float4 v0 = *(const float4*)&a3[base];
            float4 v1 = *(const float4*)&a3[base + 128];
            float4 s = make_float4(v0.x + v1.x, v0.y + v1.y, v0.z + v1.z, v0.w + v1.w);
            *(float4*)&raw[cc][x] = s;
        }
        __syncthreads();
        #pragma unroll
        for (int it = 0; it < 16; ++it) {
            int idx = it * 256 + tid;
            int j = idx & 63, cc = idx >> 6;
            pooled[cc][j] = 0.25f * (raw[cc][2 * j] + raw[cc][2 * j + 1]);
        }
        __syncthreads();
        #pragma unroll
        for (int it = 0; it < 16; ++it) {
            int cc = tid & 63;
            int jj = (tid >> 6) + it * 4;
            float val = pooled[cc][jj];
            int l = i * 64 + jj;
            int c = ct * 64 + cc;
            size_t o = (size_t)(b * LL + l) * CDIM + c;
            residual[o] = f2b(val);
            x3b[o] = f2b(val + pos[l * CDIM + c]);
        }
    } else {
        int y = blockIdx.x, b = blockIdx.z - 16;
        #pragma unroll
        for (int it = 0; it < 16; ++it) {
            int idx = it * 256 + tid;
            int x = idx & 63, cc = idx >> 6;
            pooled[cc][x] = a4[((size_t)(b * 256 + ct * 64 + cc) * 64 + y) * 64 + x];
        }
        __syncthreads();
        #pragma unroll
        for (int it = 0; it < 16; ++it) {
            int cc = tid & 63;
            int xx = (tid >> 6) + it * 4;
            int l = y * 64 + xx, c = ct * 64 + cc;
            x4b[(size_t)(b * LL + l) * CDIM + c] = f2b(pooled[cc][xx] + pos[l * CDIM + c]);
        }
    }
}

// ---------------------------------------------------------------------------
// MFMA GEMM (K=256, cols=256): out = epilogue(A @ Wt^T + bias) [+ res].
// 128 rows x 256 cols per block, 512 thr = 8 waves (2 row x 4 col), 64x64/wave.
// 2-phase double-buffered, 1 barrier/step.
template<bool DO_LN, bool DO_RELU, bool DO_RES>
__global__ __launch_bounds__(512, 4) void gemm_mfma(
    const ushort* __restrict__ A, const ushort* __restrict__ Wt,
    const float* __restrict__ bias, const float* __restrict__ gam_,
    const float* __restrict__ bet_, const ushort* __restrict__ res,
    ushort* __restrict__ outb)
{
    __shared__ ushort As[2][128 * 32];   // 8 KB each
    __shared__ ushort Bs[2][256 * 32];   // 16 KB each
    __shared__ float redS[128][4];
    __shared__ float redQ[128][4];
    __shared__ float2 mustd[128];

    const int tid = threadIdx.x;
    const int lane = tid & 63;
    const int wv = tid >> 6;     // 0..7
    const int wr = wv >> 2;      // 0..1
    const int wc = wv & 3;       // 0..3
    const int wvu = __builtin_amdgcn_readfirstlane(wv);
    const int row0 = blockIdx.x * 128;

    const int sr = tid >> 2;                      // 0..127
    const int sg = (tid & 3) ^ ((sr >> 1) & 3);   // swizzled source k-group
    const ushort* aSrc = A + (size_t)(row0 + sr) * 256 + sg * 8;
    const ushort* bSrc0 = Wt + (size_t)sr * 256 + sg * 8;
    const ushort* bSrc1 = Wt + (size_t)(128 + sr) * 256 + sg * 8;

    const int frSlot = (lane >> 4) ^ (((lane & 15) >> 1) & 3);

    f32x4 acc[4][4] = {};
    gload16(aSrc, (char*)&As[0][0] + wvu * 1024);
    gload16(bSrc0, (char*)&Bs[0][0] + wvu * 1024);
    gload16(bSrc1, (char*)&Bs[0][0] + 8192 + wvu * 1024);
    __syncthreads();

    int cur = 0;
    for (int t = 0; t < 8; ++t) {
        if (t < 7) {
            gload16(aSrc + (t + 1) * 32, (char*)&As[cur ^ 1][0] + wvu * 1024);
            gload16(bSrc0 + (t + 1) * 32, (char*)&Bs[cur ^ 1][0] + wvu * 1024);
            gload16(bSrc1 + (t + 1) * 32, (char*)&Bs[cur ^ 1][0] + 8192 + wvu * 1024);
        }
        bf16x8 af[4], bfr[4];
        #pragma unroll
        for (int f = 0; f < 4; ++f) {
            int r = wr * 64 + f * 16 + (lane & 15);
            af[f] = *(const bf16x8*)&As[cur][r * 32 + frSlot * 8];
            int c = wc * 64 + f * 16 + (lane & 15);
            bfr[f] = *(const bf16x8*)&Bs[cur][c * 32 + frSlot * 8];
        }
        __builtin_amdgcn_s_setprio(1);
        #pragma unroll
        for (int fi = 0; fi < 4; ++fi)
            #pragma unroll
            for (int fj = 0; fj < 4; ++fj)
                acc[fi][fj] = __builtin_amdgcn_mfma_f32_16x16x32_bf16(
                    af[fi], bfr[fj], acc[fi][fj], 0, 0, 0);
        __builtin_amdgcn_s_setprio(0);
        __syncthreads();
        cur ^= 1;
    }

    const int cl = lane & 15;
    const int rg = lane >> 4;
    float bia[4], gmv[4], btv[4];
    #pragma unroll
    for (int fj = 0; fj < 4; ++fj) {
        int col = wc * 64 + fj * 16 + cl;
        bia[fj] = bias[col];
        if constexpr (DO_LN) { gmv[fj] = gam_[col]; btv[fj] = bet_[col]; }
    }
    #pragma unroll
    for (int fi = 0; fi < 4; ++fi)
        #pragma unroll
        for (int fj = 0; fj < 4; ++fj)
            #pragma unroll
            for (int j = 0; j < 4; ++j)
                acc[fi][fj][j] += bia[fj];

    if constexpr (DO_LN) {
        #pragma unroll
        for (int fi = 0; fi < 4; ++fi)
            #pragma unroll
            for (int j = 0; j < 4; ++j) {
                float s = acc[fi][0][j] + acc[fi][1][j] + acc[fi][2][j] + acc[fi][3][j];
                float q = acc[fi][0][j] * acc[fi][0][j] + acc[fi][1][j] * acc[fi][1][j]
                        + acc[fi][2][j] * acc[fi][2][j] + acc[fi][3][j] * acc[fi][3][j];
                #pragma unroll
                for (int m = 1; m <= 8; m <<= 1) {
                    s += __shfl_xor(s, m, 64);
                    q += __shfl_xor(q, m, 64);
                }
                if (cl == 0) {
                    int tr = wr * 64 + fi * 16 + rg * 4 + j;
                    redS[tr][wc] = s; redQ[tr][wc] = q;
                }
            }
        __syncthreads();
        if (tid < 128) {
            float s = redS[tid][0] + redS[tid][1] + redS[tid][2] + redS[tid][3];
            float q = redQ[tid][0] + redQ[tid][1] + redQ[tid][2] + redQ[tid][3];
            float mu = s * (1.0f / 256.0f);
            float var = q * (1.0f / 256.0f) - mu * mu;
            mustd[tid] = make_float2(mu, rsqrtf(var + 1e-5f));
        }
        __syncthreads();
        #pragma unroll
        for (int fi = 0; fi < 4; ++fi)
            #pragma unroll
            for (int j = 0; j < 4; ++j) {
                float2 ms = mustd[wr * 64 + fi * 16 + rg * 4 + j];
                #pragma unroll
                for (int fj = 0; fj < 4; ++fj)
                    acc[fi][fj][j] = (acc[fi][fj][j] - ms.x) * ms.y * gmv[fj] + btv[fj];
            }
    }
    if constexpr (DO_RELU) {
        #pragma unroll
        for (int fi = 0; fi < 4; ++fi)
            #pragma unroll
            for (int fj = 0; fj < 4; ++fj)
                #pragma unroll
                for (int j = 0; j < 4; ++j)
                    acc[fi][fj][j] = fmaxf(acc[fi][fj][j], 0.0f);
    }
    #pragma unroll
    for (int fi = 0; fi < 4; ++fi)
        #pragma unroll
        for (int j = 0; j < 4; ++j) {
            size_t row = row0 + wr * 64 + fi * 16 + rg * 4 + j;
            size_t rbase = row * 256 + wc * 64 + cl;
            #pragma unroll
            for (int fj = 0; fj < 4; ++fj) {
                float v = acc[fi][fj][j];
                if constexpr (DO_RES) v += b2f(res[rbase + fj * 16]);
                outb[rbase + fj * 16] = f2b(v);
            }
        }
}

// ---------------------------------------------------------------------------
// Fused K+V GEMM (128 rows, 512 thr, dbuf): K = relu(LN(x4@k_w+k_b)), V = x4@v_w+v_b.
// Reduction scratch aliased into As (dead after K-loop) -> 80 KB LDS -> 2 blocks/CU.
__global__ __launch_bounds__(512, 2) void gemm_kv(
    const ushort* __restrict__ A, const ushort* __restrict__ wkT,
    const ushort* __restrict__ wvT, const float* __restrict__ k_b,
    const float* __restrict__ k_g, const float* __restrict__ k_beta,
    const float* __restrict__ v_b, const float* __restrict__ snc,
    float* __restrict__ ksglob, ushort* __restrict__ Kb, ushort* __restrict__ Vb)
{
    __shared__ ushort As[2][128 * 32];    // 8 KB each; epilogue reuses as scratch
    __shared__ ushort BsK[2][256 * 32];   // 16 KB each
    __shared__ ushort BsV[2][256 * 32];
    float*  redS  = (float*)&As[0][0];        // [128][4]
    float*  redQ  = redS + 512;
    float2* mustd = (float2*)(redQ + 512);

    const int tid = threadIdx.x;
    const int lane = tid & 63;
    const int wv = tid >> 6;
    const int wr = wv >> 2;
    const int wc = wv & 3;
    const int wvu = __builtin_amdgcn_readfirstlane(wv);
    const int row0 = blockIdx.x * 128;

    const int sr = tid >> 2;
    const int sg = (tid & 3) ^ ((sr >> 1) & 3);
    const ushort* aSrc = A + (size_t)(row0 + sr) * 256 + sg * 8;
    const ushort* bkSrc0 = wkT + (size_t)sr * 256 + sg * 8;
    const ushort* bkSrc1 = wkT + (size_t)(128 + sr) * 256 + sg * 8;
    const ushort* bvSrc0 = wvT + (size_t)sr * 256 + sg * 8;
    const ushort* bvSrc1 = wvT + (size_t)(128 + sr) * 256 + sg * 8;

    const int frSlot = (lane >> 4) ^ (((lane & 15) >> 1) & 3);

    f32x4 accK[4][4] = {};
    f32x4 accV[4][4] = {};
    gload16(aSrc, (char*)&As[0][0] + wvu * 1024);
    gload16(bkSrc0, (char*)&BsK[0][0] + wvu * 1024);
    gload16(bkSrc1, (char*)&BsK[0][0] + 8192 + wvu * 1024);
    gload16(bvSrc0, (char*)&BsV[0][0] + wvu * 1024);
    gload16(bvSrc1, (char*)&BsV[0][0] + 8192 + wvu * 1024);
    __syncthreads();

    int cur = 0;
    for (int t = 0; t < 8; ++t) {
        if (t < 7) {
            gload16(aSrc + (t + 1) * 32, (char*)&As[cur ^ 1][0] + wvu * 1024);
            gload16(bkSrc0 + (t + 1) * 32, (char*)&BsK[cur ^ 1][0] + wvu * 1024);
            gload16(bkSrc1 + (t + 1) * 32, (char*)&BsK[cur ^ 1][0] + 8192 + wvu * 1024);
            gload16(bvSrc0 + (t + 1) * 32, (char*)&BsV[cur ^ 1][0] + wvu * 1024);
            gload16(bvSrc1 + (t + 1) * 32, (char*)&BsV[cur ^ 1][0] + 8192 + wvu * 1024);
        }
        bf16x8 af[4], bk[4], bv[4];
        #pragma unroll
        for (int f = 0; f < 4; ++f) {
            int r = wr * 64 + f * 16 + (lane & 15);
            af[f] = *(const bf16x8*)&As[cur][r * 32 + frSlot * 8];
            int c = wc * 64 + f * 16 + (lane & 15);
            bk[f] = *(const bf16x8*)&BsK[cur][c * 32 + frSlot * 8];
            bv[f] = *(const bf16x8*)&BsV[cur][c * 32 + frSlot * 8];
        }
        __builtin_amdgcn_s_setprio(1);
        #pragma unroll
        for (int fi = 0; fi < 4; ++fi)
            #pragma unroll
            for (int fj = 0; fj < 4; ++fj) {
                accK[fi][fj] = __builtin_amdgcn_mfma_f32_16x16x32_bf16(
                    af[fi], bk[fj], accK[fi][fj], 0, 0, 0);
                accV[fi][fj] = __builtin_amdgcn_mfma_f32_16x16x32_bf16(
                    af[fi], bv[fj], accV[fi][fj], 0, 0, 0);
            }
        __builtin_amdgcn_s_setprio(0);
        __syncthreads();
        cur ^= 1;
    }

    const int cl = lane & 15;
    const int rg = lane >> 4;
    // ---- V epilogue ----
    #pragma unroll
    for (int fj = 0; fj < 4; ++fj) {
        float bv_ = v_b[wc * 64 + fj * 16 + cl];
        #pragma unroll
        for (int fi = 0; fi < 4; ++fi)
            #pragma unroll
            for (int j = 0; j < 4; ++j)
                accV[fi][fj][j] += bv_;
    }
    #pragma unroll
    for (int fi = 0; fi < 4; ++fi)
        #pragma unroll
        for (int j = 0; j < 4; ++j) {
            size_t rbase = (size_t)(row0 + wr * 64 + fi * 16 + rg * 4 + j) * 256 + wc * 64 + cl;
            #pragma unroll
            for (int fj = 0; fj < 4; ++fj)
                Vb[rbase + fj * 16] = f2b(accV[fi][fj][j]);
        }
    // ---- K epilogue: bias + LN + relu + ksum + store ----
    float bia[4], gmv[4], btv[4];
    #pragma unroll
    for (int fj = 0; fj < 4; ++fj) {
        int col = wc * 64 + fj * 16 + cl;
        bia[fj] = k_b[col]; gmv[fj] = k_g[col]; btv[fj] = k_beta[col];
    }
    #pragma unroll
    for (int fi = 0; fi < 4; ++fi)
        #pragma unroll
        for (int fj = 0; fj < 4; ++fj)
            #pragma unroll
            for (int j = 0; j < 4; ++j)
                accK[fi][fj][j] += bia[fj];
    #pragma unroll
    for (int fi = 0; fi < 4; ++fi)
        #pragma unroll
        for (int j = 0; j < 4; ++j) {
            float s = accK[fi][0][j] + accK[fi][1][j] + accK[fi][2][j] + accK[fi][3][j];
            float q = accK[fi][0][j] * accK[fi][0][j] + accK[fi][1][j] * accK[fi][1][j]
                    + accK[fi][2][j] * accK[fi][2][j] + accK[fi][3][j] * accK[fi][3][j];
            #pragma unroll
            for (int m = 1; m <= 8; m <<= 1) {
                s += __shfl_xor(s, m, 64);
                q += __shfl_xor(q, m, 64);
            }
            if (cl == 0) {
                int tr = wr * 64 + fi * 16 + rg * 4 + j;
                redS[tr * 4 + wc] = s; redQ[tr * 4 + wc] = q;
            }
        }
    __syncthreads();
    if (tid < 128) {
        float s = redS[tid * 4] + redS[tid * 4 + 1] + redS[tid * 4 + 2] + redS[tid * 4 + 3];
        float q = redQ[tid * 4] + redQ[tid * 4 + 1] + redQ[tid * 4 + 2] + redQ[tid * 4 + 3];
        float mu = s * (1.0f / 256.0f);
        float var = q * (1.0f / 256.0f) - mu * mu;
        mustd[tid] = make_float2(mu, rsqrtf(var + 1e-5f));
    }
    __syncthreads();
    float kss[4] = {}, ksc[4] = {};
    #pragma unroll
    for (int fi = 0; fi < 4; ++fi)
        #pragma unroll
        for (int j = 0; j < 4; ++j) {
            int rloc = wr * 64 + fi * 16 + rg * 4 + j;
            float2 ms = mustd[rloc];
            int l = (row0 + rloc) & (LL - 1);
            float sn = snc[l * 2], cs = snc[l * 2 + 1];
            size_t rbase = (size_t)(row0 + rloc) * 256 + wc * 64 + cl;
            #pragma unroll
            for (int fj = 0; fj < 4; ++fj) {
                float v = (accK[fi][fj][j] - ms.x) * ms.y * gmv[fj] + btv[fj];
                v = fmaxf(v, 0.0f);
                Kb[rbase + fj * 16] = f2b(v);
                kss[fj] += sn * v;
                ksc[fj] += cs * v;
            }
        }
    int b = row0 >> 12;
    #pragma unroll
    for (int fj = 0; fj < 4; ++fj) {
        float s = kss[fj], c = ksc[fj];
        s += __shfl_xor(s, 16, 64); s += __shfl_xor(s, 32, 64);
        c += __shfl_xor(c, 16, 64); c += __shfl_xor(c, 32, 64);
        if (rg == 0) {
            int col = wc * 64 + fj * 16 + cl;
            atomicAdd(&ksglob[((size_t)b * 2 + 0) * 256 + col], s);
            atomicAdd(&ksglob[((size_t)b * 2 + 1) * 256 + col], c);
        }
    }
}

// ---------------------------------------------------------------------------
// Fused MLP: out = LN2(gelu(res2@W1+b1)@W2+b2) + res2.
// 64 rows/block, 4 chunks of 256 h1-cols; h1 chunk in LDS as [t][64][36] (padded).
__global__ __launch_bounds__(256, 2) void mlp_fused(
    const ushort* __restrict__ res2, const ushort* __restrict__ w1T,
    const ushort* __restrict__ w2T, const float* __restrict__ b1,
    const float* __restrict__ b2, const float* __restrict__ gam_,
    const float* __restrict__ bet_, ushort* __restrict__ outb)
{
    __shared__ ushort As[2][64 * 32];
    __shared__ ushort Bs[2][256 * 32];
    __shared__ ushort h1c[8 * 64 * 36];   // 36 KB, 72B row stride (odd dword count)
    __shared__ float redS[64][4];
    __shared__ float redQ[64][4];
    __shared__ float2 mustd[64];

    const int tid = threadIdx.x;
    const int lane = tid & 63;
    const int wv = tid >> 6;
    const int wvu = __builtin_amdgcn_readfirstlane(wv);
    const int row0 = blockIdx.x * 64;
    const int sr = tid >> 2;
    const int sg = (tid & 3) ^ ((sr >> 1) & 3);
    const ushort* aSrc = res2 + (size_t)(row0 + sr) * 256 + sg * 8;
    const int frSlot = (lane >> 4) ^ (((lane & 15) >> 1) & 3);
    const int cl = lane & 15;
    const int rg = lane >> 4;

    f32x4 acc2[4][4] = {};
    gload16(aSrc, (char*)&As[0][0] + wvu * 1024);
    #pragma unroll
    for (int j = 0; j < 4; ++j)
        gload16(w1T + (size_t)(j * 64 + sr) * 256 + sg * 8,
                (char*)&Bs[0][0] + j * 4096 + wvu * 1024);
    __syncthreads();
    int cur = 0;

    for (int c = 0; c < 4; ++c) {
        const ushort* b1Src = w1T + (size_t)(c * 256 + sr) * 256 + sg * 8;
        const ushort* b2Src = w2T + (size_t)sr * 1024 + c * 256 + sg * 8;
        f32x4 acc1[4][4] = {};
        // ---- GEMM1 over K=256 (8 steps) ----
        for (int t = 0; t < 8; ++t) {
            if (t < 7) {
                gload16(aSrc + (t + 1) * 32, (char*)&As[cur ^ 1][0] + wvu * 1024);
                #pragma unroll
                for (int j = 0; j < 4; ++j)
                    gload16(b1Src + j * 64 * 256 + (t + 1) * 32,
                            (char*)&Bs[cur ^ 1][0] + j * 4096 + wvu * 1024);
            } else {
                gload16(aSrc, (char*)&As[cur ^ 1][0] + wvu * 1024);
                #pragma unroll
                for (int j = 0; j < 4; ++j)
                    gload16(b2Src + (size_t)j * 64 * 1024,
                            (char*)&Bs[cur ^ 1][0] + j * 4096 + wvu * 1024);
            }
            bf16x8 af[4], bfr[4];
            #pragma unroll
            for (int f = 0; f < 4; ++f) {
                int r = f * 16 + (lane & 15);
                af[f] = *(const bf16x8*)&As[cur][r * 32 + frSlot * 8];
                int cc2 = wv * 64 + f * 16 + (lane & 15);
                bfr[f] = *(const bf16x8*)&Bs[cur][cc2 * 32 + frSlot * 8];
            }
            __builtin_amdgcn_s_setprio(1);
            #pragma unroll
            for (int fi = 0; fi < 4; ++fi)
                #pragma unroll
                for (int fj = 0; fj < 4; ++fj)
                    acc1[fi][fj] = __builtin_amdgcn_mfma_f32_16x16x32_bf16(
                        af[fi], bfr[fj], acc1[fi][fj], 0, 0, 0);
            __builtin_amdgcn_s_setprio(0);
            __syncthreads();
            cur ^= 1;
        }
        // ---- epilogue1: bias + fast gelu -> h1c ----
        float bia1[4];
        #pragma unroll
        for (int fj = 0; fj < 4; ++fj)
            bia1[fj] = b1[c * 256 + wv * 64 + fj * 16 + cl];
        #pragma unroll
        for (int fi = 0; fi < 4; ++fi)
            #pragma unroll
            for (int fj = 0; fj < 4; ++fj) {
                int tch = wv * 2 + (fj >> 1);
                int kk_local = (fj & 1) * 16 + cl;
                #pragma unroll
                for (int j = 0; j < 4; ++j) {
                    float v = acc1[fi][fj][j] + bia1[fj];
                    float g = fast_gelu(v);
                    int row = fi * 16 + rg * 4 + j;
                    h1c[tch * 2304 + row * 36 + kk_local] = f2b(g);
                }
            }
        __syncthreads();
        // ---- GEMM2 over this chunk's K=256 (8 steps) ----
        for (int t = 0; t < 8; ++t) {
            if (t < 7) {
                #pragma unroll
                for (int j = 0; j < 4; ++j)
                    gload16(b2Src + (size_t)j * 64 * 1024 + (t + 1) * 32,
                            (char*)&Bs[cur ^ 1][0] + j * 4096 + wvu * 1024);
            } else {
                int cn = (c < 3) ? c + 1 : 3;
                #pragma unroll
                for (int j = 0; j < 4; ++j)
                    gload16(w1T + (size_t)(cn * 256 + j * 64 + sr) * 256 + sg * 8,
                            (char*)&Bs[cur ^ 1][0] + j * 4096 + wvu * 1024);
            }
            bf16x8 af[4], bfr[4];
            #pragma unroll
            for (int f = 0; f < 4; ++f) {
                int r = f * 16 + (lane & 15);
                int ho = t * 2304 + r * 36 + (lane >> 4) * 8;
                bf16x4 lo = *(const bf16x4*)&h1c[ho];
                bf16x4 hi = *(const bf16x4*)&h1c[ho + 4];
                bf16x8 a_;
                a_[0] = lo[0]; a_[1] = lo[1]; a_[2] = lo[2]; a_[3] = lo[3];
                a_[4] = hi[0]; a_[5] = hi[1]; a_[6] = hi[2]; a_[7] = hi[3];
                af[f] = a_;
                int cc2 = wv * 64 + f * 16 + (lane & 15);
                bfr[f] = *(const bf16x8*)&Bs[cur][cc2 * 32 + frSlot * 8];
            }
            __builtin_amdgcn_s_setprio(1);
            #pragma unroll
            for (int fi = 0; fi < 4; ++fi)
                #pragma unroll
                for (int fj = 0; fj < 4; ++fj)
                    acc2[fi][fj] = __builtin_amdgcn_mfma_f32_16x16x32_bf16(
                        af[fi], bfr[fj], acc2[fi][fj], 0, 0, 0);
            __builtin_amdgcn_s_setprio(0);
            __syncthreads();
            cur ^= 1;
        }
    }
    // ---- epilogue2: + b2, LN(n2), + res2 residual, write bf16 ----
    float bia[4], gmv[4], btv[4];
    #pragma unroll
    for (int fj = 0; fj < 4; ++fj) {
        int col = wv * 64 + fj * 16 + cl;
        bia[fj] = b2[col];
        gmv[fj] = gam_[col];
        btv[fj] = bet_[col];
    }
    #pragma unroll
    for (int fi = 0; fi < 4; ++fi)
        #pragma unroll
        for (int fj = 0; fj < 4; ++fj)
            #pragma unroll
            for (int j = 0; j < 4; ++j)
                acc2[fi][fj][j] += bia[fj];
    #pragma unroll
    for (int fi = 0; fi < 4; ++fi)
        #pragma unroll
        for (int j = 0; j < 4; ++j) {
            float s = acc2[fi][0][j] + acc2[fi][1][j] + acc2[fi][2][j] + acc2[fi][3][j];
            float q = acc2[fi][0][j] * acc2[fi][0][j] + acc2[fi][1][j] * acc2[fi][1][j]
                    + acc2[fi][2][j] * acc2[fi][2][j] + acc2[fi][3][j] * acc2[fi][3][j];
            #pragma unroll
            for (int m = 1; m <= 8; m <<= 1) {
                s += __shfl_xor(s, m, 64);
                q += __shfl_xor(q, m, 64);
            }
            if (cl == 0) { redS[fi * 16 + rg * 4 + j][wv] = s; redQ[fi * 16 + rg * 4 + j][wv] = q; }
        }
    __syncthreads();
    if (tid < 64) {
        float s = redS[tid][0] + redS[tid][1] + redS[tid][2] + redS[tid][3];
        float q = redQ[tid][0] + redQ[tid][1] + redQ[tid][2] + redQ[tid][3];
        float mu = s * (1.0f / 256.0f);
        float var = q * (1.0f / 256.0f) - mu * mu;
        mustd[tid] = make_float2(mu, rsqrtf(var + 1e-5f));
    }
    __syncthreads();
    #pragma unroll
    for (int fi = 0; fi < 4; ++fi)
        #pragma unroll
        for (int j = 0; j < 4; ++j) {
            float2 ms = mustd[fi * 16 + rg * 4 + j];
            size_t row = row0 + fi * 16 + rg * 4 + j;
            size_t rbase = row * 256 + wv * 64 + cl;
            #pragma unroll
            for (int fj = 0; fj < 4; ++fj) {
                float v = (acc2[fi][fj][j] - ms.x) * ms.y * gmv[fj] + btv[fj];
                v += b2f(res2[rbase + fj * 16]);
                outb[rbase + fj * 16] = f2b(v);
            }
        }
}

// ---------------------------------------------------------------------------
// cosFormer stage 1: partial KVs/KVc (32x32) per (b,h,chunk). Stride 2048.
__global__ __launch_bounds__(256) void kv_kernel(
    const ushort* __restrict__ Kmat, const ushort* __restrict__ Vmat,
    const float* __restrict__ snc, float* __restrict__ kvpart)
{
    __shared__ float Kt[64][36];
    __shared__ float Vt[64][36];
    __shared__ float sns[64], css[64];
    int chunk = blockIdx.x;
    int bh = blockIdx.y;
    int b = bh >> 3, h = bh & 7;
    int tid = threadIdx.x;
    int m = tid & 31;
    int d0 = (tid >> 5) * 4;
    float accs[4] = {}, accc[4] = {};
    int l0chunk = chunk * 512;
    int lrow = tid >> 2;
    int lcol = (tid & 3) * 8;
    for (int sub = 0; sub < 8; ++sub) {
        int l0 = l0chunk + sub * 64;
        {
            size_t gbase = (size_t)(b * LL + l0 + lrow) * CDIM + h * 32 + lcol;
            uint4 kr = *(const uint4*)&Kmat[gbase];
            uint4 vr = *(const uint4*)&Vmat[gbase];
            float* kd = &Kt[lrow][lcol];
            float* vd = &Vt[lrow][lcol];
            kd[0] = b2f((ushort)(kr.x & 0xffff)); kd[1] = b2f((ushort)(kr.x >> 16));
            kd[2] = b2f((ushort)(kr.y & 0xffff)); kd[3] = b2f((ushort)(kr.y >> 16));
            kd[4] = b2f((ushort)(kr.z & 0xffff)); kd[5] = b2f((ushort)(kr.z >> 16));
            kd[6] = b2f((ushort)(kr.w & 0xffff)); kd[7] = b2f((ushort)(kr.w >> 16));
            vd[0] = b2f((ushort)(vr.x & 0xffff)); vd[1] = b2f((ushort)(vr.x >> 16));
            vd[2] = b2f((ushort)(vr.y & 0xffff)); vd[3] = b2f((ushort)(vr.y >> 16));
            vd[4] = b2f((ushort)(vr.z & 0xffff)); vd[5] = b2f((ushort)(vr.z >> 16));
            vd[6] = b2f((ushort)(vr.w & 0xffff)); vd[7] = b2f((ushort)(vr.w >> 16));
        }
        if (tid < 64) { sns[tid] = snc[(l0 + tid) * 2]; css[tid] = snc[(l0 + tid) * 2 + 1]; }
        __syncthreads();
        #pragma unroll 4
        for (int lt = 0; lt < 64; ++lt) {
            float v = Vt[lt][m];
            float vs = v * sns[lt];
            float vc = v * css[lt];
            float4 kd4 = *(const float4*)&Kt[lt][d0];
            accs[0] += kd4.x * vs; accc[0] += kd4.x * vc;
            accs[1] += kd4.y * vs; accc[1] += kd4.y * vc;
            accs[2] += kd4.z * vs; accc[2] += kd4.z * vc;
            accs[3] += kd4.w * vs; accc[3] += kd4.w * vc;
        }
        __syncthreads();
    }
    size_t base = (size_t)(bh * 8 + chunk) * 2048;
    #pragma unroll
    for (int i2 = 0; i2 < 4; ++i2) {
        kvpart[base + (d0 + i2) * 32 + m] = accs[i2];
        kvpart[base + 1024 + (d0 + i2) * 32 + m] = accc[i2];
    }
}

// ---------------------------------------------------------------------------
// Reduce chunk partials into per-(b,h) MFMA B-image, hi/lo bf16 split.
__global__ __launch_bounds__(256) void kvred_kernel(
    const float* __restrict__ kvpart, const float* __restrict__ ksglob,
    ushort* __restrict__ Bimg)
{
    int bh = blockIdx.x;
    int b = bh >> 3, h = bh & 7;
    int tid = threadIdx.x;
    for (int e = tid; e < 2560; e += 256) {
        int n = e >> 5;
        int k = e & 31;
        int t = n >> 4, col = n & 15;
        float v = 0.0f;
        if (t < 4) {
            int off = (t >= 2 ? 1024 : 0) + k * 32 + (t & 1) * 16 + col;
            #pragma unroll
            for (int ch = 0; ch < 8; ++ch)
                v += kvpart[(size_t)(bh * 8 + ch) * 2048 + off];
        } else if (col < 2) {
            v = ksglob[((size_t)b * 2 + col) * 256 + h * 32 + k];
        }
        ushort hi = f2b(v);
        ushort lo = f2b(v - b2f(hi));
        Bimg[(size_t)bh * 5120 + n * 32 + k] = hi;
        Bimg[(size_t)bh * 5120 + (80 + n) * 32 + k] = lo;
    }
}

// ---------------------------------------------------------------------------
// attn via MFMA: per (ltile, h, b): 256 rows.
__global__ __launch_bounds__(256, 2) void attn_mfma(
    const ushort* __restrict__ Qmat, const ushort* __restrict__ Bimg,
    const float* __restrict__ snc, ushort* __restrict__ attnOut)
{
    __shared__ ushort Bs[5120];
    int ltile = blockIdx.x, h = blockIdx.y, b = blockIdx.z;
    int bh = b * 8 + h;
    int tid = threadIdx.x;
    int lane = tid & 63;
    int wv = tid >> 6;

    for (int e = tid; e < 640; e += 256)
        *(uint4*)&Bs[e * 8] = *(const uint4*)&Bimg[(size_t)bh * 5120 + e * 8];
    __syncthreads();

    bf16x8 bfr[10];
    #pragma unroll
    for (int tt = 0; tt < 10; ++tt) {
        int row = (tt < 5 ? tt * 16 : 80 + (tt - 5) * 16) + (lane & 15);
        bfr[tt] = *(const bf16x8*)&Bs[row * 32 + (lane >> 4) * 8];
    }
    int lbase = ltile * 256 + wv * 64;
    bf16x8 af[4];
    #pragma unroll
    for (int fi = 0; fi < 4; ++fi) {
        int l = lbase + fi * 16 + (lane & 15);
        af[fi] = *(const bf16x8*)&Qmat[(size_t)(b * LL + l) * CDIM + h * 32 + (lane >> 4) * 8];
    }
    f32x4 acc[4][5] = {};
    __builtin_amdgcn_s_setprio(1);
    #pragma unroll
    for (int fi = 0; fi < 4; ++fi)
        #pragma unroll
        for (int t = 0; t < 5; ++t) {
            acc[fi][t] = __builtin_amdgcn_mfma_f32_16x16x32_bf16(af[fi], bfr[t], acc[fi][t], 0, 0, 0);
            acc[fi][t] = __builtin_amdgcn_mfma_f32_16x16x32_bf16(af[fi], bfr[t + 5], acc[fi][t], 0, 0, 0);
        }
    __builtin_amdgcn_s_setprio(0);

    int zlane = lane & 48;
    int cl = lane & 15;
    #pragma unroll
    for (int fi = 0; fi < 4; ++fi) {
        #pragma unroll
        for (int j = 0; j < 4; ++j) {
            float zraw = acc[fi][4][j];
            float zs = __shfl(zraw, zlane, 64);
            float zc = __shfl(zraw, zlane | 1, 64);
            int l = lbase + fi * 16 + ((lane >> 4) & 3) * 4 + j;
            float sn = snc[l * 2], cs = snc[l * 2 + 1];
            float den = sn * zs + cs * zc;
            float Z = 1.0f / fmaxf(den, 1e-6f);
            float v0 = (sn * acc[fi][0][j] + cs * acc[fi][2][j]) * Z;
            float v1 = (sn * acc[fi][1][j] + cs * acc[fi][3][j]) * Z;
            size_t ob = (size_t)(b * LL + l) * CDIM + h * 32 + cl;
            attnOut[ob] = f2b(v0);
            attnOut[ob + 16] = f2b(v1);
        }
    }
}

// ---------------------------------------------------------------------------
// ffeat bf16 (b,L,256) -> (b,c,64,64) -> bilinear x2 * a3 -> out f32
// Vectorized ffeat loads: uint4 = 8 bf16 per load (6 loads/thread).
__global__ __launch_bounds__(256) void resize_mul_kernel(
    const ushort* __restrict__ ffeat, const float* __restrict__ a3, float* __restrict__ out)
{
    __shared__ float ft[3][64][65];
    int k = blockIdx.x, ct = blockIdx.y, b = blockIdx.z;
    int tid = threadIdx.x;
    #pragma unroll
    for (int it = 0; it < 6; ++it) {
        int e = it * 256 + tid;        // 0..1535
        int cg = e & 7;                // col-group of 8 bf16
        int xs = (e >> 3) & 63;
        int ys = e >> 9;               // 0..2
        int ysrc = min(max(k - 1 + ys, 0), 63);
        uint4 raw = *(const uint4*)&ffeat[(size_t)(b * LL + ysrc * 64 + xs) * CDIM + ct * 64 + cg * 8];
        float* dst = &ft[ys][cg * 8][xs];
        dst[0]   = b2f((ushort)(raw.x & 0xffff)); dst[65]  = b2f((ushort)(raw.x >> 16));
        dst[130] = b2f((ushort)(raw.y & 0xffff)); dst[195] = b2f((ushort)(raw.y >> 16));
        dst[260] = b2f((ushort)(raw.z & 0xffff)); dst[325] = b2f((ushort)(raw.z >> 16));
        dst[390] = b2f((ushort)(raw.w & 0xffff)); dst[455] = b2f((ushort)(raw.w >> 16));
    }
    __syncthreads();
    int x = tid & 127;
    int half = tid >> 7;
    int y = 2 * k + half;
    int ysA, ysB; float wyA, wyB;
    if (half == 0) { ysA = 0; ysB = 1; wyA = 0.25f; wyB = 0.75f; }
    else           { ysA = 1; ysB = 2; wyA = 0.75f; wyB = 0.25f; }
    int x0; float wx1;
    if ((x & 1) == 0) { x0 = x / 2 - 1; wx1 = 0.75f; }
    else              { x0 = x / 2;     wx1 = 0.25f; }
    int x0c = max(x0, 0);
    int x1c = min(x0 + 1, 63);
    float wx0 = 1.0f - wx1;
    for (int cc = 0; cc < 64; ++cc) {
        float rA = wx0 * ft[ysA][cc][x0c] + wx1 * ft[ysA][cc][x1c];
        float rB = wx0 * ft[ysB][cc][x0c] + wx1 * ft[ysB][cc][x1c];
        float val = wyA * rA + wyB * rB;
        size_t oidx = ((size_t)(b * 256 + ct * 64 + cc) * 128 + y) * 128 + x;
        out[oidx] = val * a3[oidx];
    }
}

// ---------------------------------------------------------------------------
extern "C" void kernel_launch(void* const* d_in, const int* in_sizes, int n_in,
                              void* d_out, int out_size, void* d_ws, size_t ws_size,
                              hipStream_t stream)
{
    const float* a3     = (const float*)d_in[0];
    const float* a4     = (const float*)d_in[1];
    const float* q_w    = (const float*)d_in[2];
    const float* q_b    = (const float*)d_in[3];
    const float* q_ln_g = (const float*)d_in[4];
    const float* q_ln_b = (const float*)d_in[5];
    const float* k_w    = (const float*)d_in[6];
    const float* k_b    = (const float*)d_in[7];
    const float* k_ln_g = (const float*)d_in[8];
    const float* k_ln_b = (const float*)d_in[9];
    const float* v_w    = (const float*)d_in[10];
    const float* v_b    = (const float*)d_in[11];
    const float* out_w  = (const float*)d_in[12];
    const float* out_b  = (const float*)d_in[13];
    const float* lin1_w = (const float*)d_in[14];
    const float* lin1_b = (const float*)d_in[15];
    const float* lin2_w = (const float*)d_in[16];
    const float* lin2_b = (const float*)d_in[17];
    const float* n1_g   = (const float*)d_in[18];
    const float* n1_b   = (const float*)d_in[19];
    const float* n2_g   = (const float*)d_in[20];
    const float* n2_b   = (const float*)d_in[21];
    float* out = (float*)d_out;
    char* base = (char*)d_ws;

    const size_t MiB = 1024 * 1024;
    float*  pos      = (float*)(base);                       // 4 MiB
    float*  snc      = (float*)(base + 4 * MiB);             // 32 KiB
    ushort* wqT      = (ushort*)(base + 4 * MiB + 64 * 1024);
    ushort* wkT      = wqT + 256 * 256;
    ushort* wvT      = wkT + 256 * 256;
    ushort* woT      = wvT + 256 * 256;
    ushort* w1T      = woT + 256 * 256;       // [1024][256]
    ushort* w2T      = w1T + 1024 * 256;      // [256][1024]
    ushort* residual = (ushort*)(base + 6 * MiB);            // 32 MiB (ffeat reuses)
    ushort* x3b      = (ushort*)(base + 38 * MiB);           // 32 MiB (attnb reuses)
    ushort* x4b      = (ushort*)(base + 70 * MiB);           // 32 MiB (res2b reuses)
    ushort* Qb       = (ushort*)(base + 102 * MiB);
    ushort* Kb       = (ushort*)(base + 134 * MiB);
    ushort* Vb       = (ushort*)(base + 166 * MiB);
    float*  kvp      = (float*)(base + 198 * MiB);           // 8 MiB
    float*  ksglob   = (float*)(base + 206 * MiB);           // 32 KiB
    ushort* Bimg     = (ushort*)(base + 207 * MiB);          // 1.25 MiB
    ushort* attnb    = x3b;
    ushort* res2b    = x4b;
    ushort* ffeat    = residual;

    prep_kernel<<<1793, 256, 0, stream>>>(pos, snc, q_w, k_w, v_w, out_w, lin1_w, lin2_w,
                                          wqT, wkT, wvT, woT, w1T, w2T, ksglob);
    pool_x4_kernel<<<dim3(64, 4, 32), 256, 0, stream>>>(a3, a4, residual, x3b, x4b, pos);

    gemm_mfma<true, true, false><<<NROWS / 128, 512, 0, stream>>>(
        x3b, wqT, q_b, q_ln_g, q_ln_b, nullptr, Qb);
    gemm_kv<<<NROWS / 128, 512, 0, stream>>>(
        x4b, wkT, wvT, k_b, k_ln_g, k_ln_b, v_b, snc, ksglob, Kb, Vb);

    kv_kernel<<<dim3(8, 128), 256, 0, stream>>>(Kb, Vb, snc, kvp);
    kvred_kernel<<<128, 256, 0, stream>>>(kvp, ksglob, Bimg);
    attn_mfma<<<dim3(16, 8, 16), 256, 0, stream>>>(Qb, Bimg, snc, attnb);

    // out-proj + LN(n1) + residual -> res2 (bf16)
    gemm_mfma<true, false, true><<<NROWS / 128, 512, 0, stream>>>(
        attnb, woT, out_b, n1_g, n1_b, residual, res2b);
    // fused MLP -> ffeat
    mlp_fused<<<NROWS / 64, 256, 0, stream>>>(
        res2b, w1T, w2T, lin1_b, lin2_b, n2_g, n2_b, ffeat);

    resize_mul_kernel<<<dim3(64, 4, 16), 256, 0, stream>>>(ffeat, a3, out);
}